// Round 16
// baseline (228.777 us; speedup 1.0000x reference)
//
#include <hip/hip_runtime.h>

namespace {

constexpr int HW = 16384;   // pixels per image
constexpr int C  = 192;
constexpr int C3 = 576;
constexpr int CH = 48;
constexpr int K  = 192;

using bf16x8 = __attribute__((ext_vector_type(8))) short;
using f32x4  = __attribute__((ext_vector_type(4))) float;

__device__ inline unsigned short f2bf(float f) {
  unsigned u = __float_as_uint(f);
  unsigned r = (u + 0x7fff + ((u >> 16) & 1)) >> 16;
  return (unsigned short)r;
}
__device__ inline float bf2f(unsigned short b) {
  return __uint_as_float(((unsigned)b) << 16);
}
__device__ inline float4 ld_bf4(const unsigned short* p) {
  const ushort4 u = *(const ushort4*)p;
  return make_float4(bf2f(u.x), bf2f(u.y), bf2f(u.z), bf2f(u.w));
}

// async global->LDS, 16B per lane. LDS dest = wave-uniform base + lane*16.
__device__ __forceinline__ void ld_g2l16(const unsigned short* g, unsigned short* l) {
  __builtin_amdgcn_global_load_lds(
      (const __attribute__((address_space(1))) unsigned int*)(unsigned long long)(const void*)g,
      (__attribute__((address_space(3))) unsigned int*)(unsigned int)(unsigned long long)(void*)l,
      16, 0, 0);
}

// slot swizzle (depends only on row mod 16)
__device__ __forceinline__ int swz4(int r) { return (r & 3) ^ ((r >> 2) & 3); }

// ---- transpose + split qkv weights: [192,576] -> hi/lo [576][192] ----------
__global__ __launch_bounds__(256) void cvt_wqkv(const float* __restrict__ wqkv,
                                                unsigned short* __restrict__ wqh,
                                                unsigned short* __restrict__ wql) {
  const int t = blockIdx.x * 256 + threadIdx.x;  // 0 .. 576*192-1
  const int n = t / 192;
  const int k = t % 192;
  const float v = wqkv[k * C3 + n];
  const unsigned short h = f2bf(v);
  wqh[n * 192 + k] = h;
  wql[n * 192 + k] = f2bf(v - bf2f(h));
}

// ---- MFMA GEMM: Co[M, NT*64] = A[M,192] @ (Bh+Bl)[NT*64,192]^T, 2-pass -----
// Block = 64 rows x ALL n-tiles. Phase 1: A staged once -> registers
// (fah[6][2], static indices). Phase 2: BARRIER-FREE — each wave loads its B
// fragments directly global->VGPR (L2-resident, 442 KB), ping-pong buffered.
template <int NT, bool PERB, bool OBF16, bool CVTA>
__global__ __launch_bounds__(256) void gemm_mfma(const void* __restrict__ Ap,
                                                 const unsigned short* __restrict__ Bh,
                                                 const unsigned short* __restrict__ Bl,
                                                 void* __restrict__ Co) {
  constexpr int N = NT * 64;
  __shared__ __align__(16) unsigned short sA[64 * 32];
  const int t = threadIdx.x;
  const int lane = t & 63;
  const int wv = t >> 6;
  const int m0 = blockIdx.x * 64;
  const size_t boff = PERB ? (size_t)(m0 >> 14) * (192 * 192) : 0;
  const int wr = wv >> 1, wc = wv & 1;        // 2x2 waves over 64x64
  const int fr_row = lane & 15;
  const int fr_swz = (((lane >> 4) ^ swz4(fr_row)) & 3) << 3;
  const int kslc = (lane >> 4) << 3;          // k-slice within 32-step
  const int lrow  = lane >> 2;                // 0..15 within wave
  const int lslot = lane & 3;
  const int srow0 = wv * 16;                  // staging rows per wave
  const int ssl   = (lslot ^ swz4(lrow)) & 3; // stage-side slot (row mod 16)

  // ---- phase 1: A -> registers, staged k-step by k-step --------------------
  bf16x8 fah[6][2];
#pragma unroll
  for (int ks = 0; ks < 6; ++ks) {
    const int k0 = ks * 32;
    if constexpr (CVTA) {
      const int row = t >> 2;                 // 0..63
      const int sl  = t & 3;
      const int sphys = (sl ^ swz4(row & 15)) & 3;
      const float* src = &((const float*)Ap)[(size_t)(m0 + row) * K + k0 + (sl << 3)];
      const float4 f0 = *(const float4*)src;
      const float4 f1 = *(const float4*)(src + 4);
      bf16x8 h;
      h[0] = (short)f2bf(f0.x); h[1] = (short)f2bf(f0.y);
      h[2] = (short)f2bf(f0.z); h[3] = (short)f2bf(f0.w);
      h[4] = (short)f2bf(f1.x); h[5] = (short)f2bf(f1.y);
      h[6] = (short)f2bf(f1.z); h[7] = (short)f2bf(f1.w);
      *(bf16x8*)&sA[row * 32 + (sphys << 3)] = h;
    } else {
      const size_t go = (size_t)(m0 + srow0 + lrow) * K + k0 + (ssl << 3);
      ld_g2l16(&((const unsigned short*)Ap)[go], &sA[srow0 * 32]);
    }
    __syncthreads();
#pragma unroll
    for (int i = 0; i < 2; ++i) {
      const int row = wr * 32 + i * 16 + fr_row;
      fah[ks][i] = *(const bf16x8*)&sA[row * 32 + fr_swz];
    }
    __syncthreads();
  }

  // ---- phase 2: barrier-free n-tile loop, B direct global->VGPR ------------
  auto loadB = [&](int nt_, int ks_, bf16x8* bh, bf16x8* bl) {
#pragma unroll
    for (int j = 0; j < 2; ++j) {
      const size_t go = boff + (size_t)(nt_ * 64 + wc * 32 + j * 16 + fr_row) * K
                      + ks_ * 32 + kslc;
      bh[j] = *(const bf16x8*)&Bh[go];
      bl[j] = *(const bf16x8*)&Bl[go];
    }
  };

  bf16x8 bh[2][2], bl[2][2];
  loadB(0, 0, bh[0], bl[0]);
  const int er = (lane >> 4) << 2;  // C/D: col=lane&15, row=(lane>>4)*4+reg
  const int ec = lane & 15;
  for (int nt = 0; nt < NT; ++nt) {
    f32x4 acc[2][2] = {};
#pragma unroll
    for (int ks = 0; ks < 6; ++ks) {
      const int cur = ks & 1, nxt = cur ^ 1;
      const bool last = (nt == NT - 1) && (ks == 5);
      if (!last) {
        if (ks < 5) loadB(nt, ks + 1, bh[nxt], bl[nxt]);
        else        loadB(nt + 1, 0, bh[nxt], bl[nxt]);
      }
#pragma unroll
      for (int i = 0; i < 2; ++i)
#pragma unroll
        for (int j = 0; j < 2; ++j) {
          acc[i][j] = __builtin_amdgcn_mfma_f32_16x16x32_bf16(fah[ks][i], bh[cur][j], acc[i][j], 0, 0, 0);
          acc[i][j] = __builtin_amdgcn_mfma_f32_16x16x32_bf16(fah[ks][i], bl[cur][j], acc[i][j], 0, 0, 0);
        }
    }
#pragma unroll
    for (int i = 0; i < 2; ++i)
#pragma unroll
      for (int j = 0; j < 2; ++j) {
        const size_t base = (size_t)(m0 + wr * 32 + i * 16 + er) * N + nt * 64 + wc * 32 + j * 16 + ec;
        if constexpr (OBF16) {
          unsigned short* cp = (unsigned short*)Co + base;
#pragma unroll
          for (int r = 0; r < 4; ++r) cp[(size_t)r * N] = f2bf(acc[i][j][r]);
        } else {
          float* cp = (float*)Co + base;
#pragma unroll
          for (int r = 0; r < 4; ++r) cp[(size_t)r * N] = acc[i][j][r];
        }
      }
  }
}

// ---- depthwise 3x3 SAME, rolling-window TY=8, bf16 in/out ------------------
// q,k -> bf16 qk[p][384]; v -> bf16 vh[p][192]
constexpr int TY = 8;
__global__ __launch_bounds__(256) void dwconv3x3_v5(const unsigned short* __restrict__ in,
                                                    const float* __restrict__ wdw,
                                                    unsigned short* __restrict__ qk,
                                                    unsigned short* __restrict__ vh) {
  const int t = blockIdx.x * 256 + threadIdx.x;
  const int c4 = t % 144;
  const int rest = t / 144;          // (img, ystrip, x)
  const int x = rest & 127;
  const int ys = (rest >> 7) & 15;   // 16 strips of TY=8
  const int img = rest >> 11;
  const int y0 = ys * TY;

  float4 wt[3][3];
#pragma unroll
  for (int i = 0; i < 3; ++i)
#pragma unroll
    for (int j = 0; j < 3; ++j)
      wt[i][j] = *(const float4*)&wdw[(size_t)(i * 3 + j) * C3 + c4 * 4];

  const bool xm = x > 0, xp = x < 127;
  const unsigned short* ibase = &in[((size_t)((img << 14) + x)) * C3 + c4 * 4];
  const float4 z4 = make_float4(0.f, 0.f, 0.f, 0.f);
  const ptrdiff_t dxm = xm ? -(ptrdiff_t)C3 : 0;   // clamped ptr + select-zero
  const ptrdiff_t dxp = xp ? (ptrdiff_t)C3 : 0;

  auto ldrow = [&](int yy, float4* r) {
    if ((unsigned)yy < 128u) {
      const unsigned short* rp = ibase + (size_t)yy * (128 * C3);
      float4 a = ld_bf4(rp + dxm);
      float4 m = ld_bf4(rp);
      float4 b = ld_bf4(rp + dxp);
      if (!xm) a = z4;
      if (!xp) b = z4;
      r[0] = a; r[1] = m; r[2] = b;
    } else {
      r[0] = z4; r[1] = z4; r[2] = z4;
    }
  };

  float4 r0[3], r1[3], r2[3], rn[3];
  ldrow(y0 - 1, r0);
  ldrow(y0, r1);
  ldrow(y0 + 1, r2);

#pragma unroll
  for (int i = 0; i < TY; ++i) {
    if (i < TY - 1) ldrow(y0 + i + 2, rn);  // prefetch overlaps compute below
    float4 o = z4;
#pragma unroll
    for (int j = 0; j < 3; ++j) {
      o.x += r0[j].x * wt[0][j].x; o.y += r0[j].y * wt[0][j].y;
      o.z += r0[j].z * wt[0][j].z; o.w += r0[j].w * wt[0][j].w;
      o.x += r1[j].x * wt[1][j].x; o.y += r1[j].y * wt[1][j].y;
      o.z += r1[j].z * wt[1][j].z; o.w += r1[j].w * wt[1][j].w;
      o.x += r2[j].x * wt[2][j].x; o.y += r2[j].y * wt[2][j].y;
      o.z += r2[j].z * wt[2][j].z; o.w += r2[j].w * wt[2][j].w;
    }
    const int p = (img << 14) + ((y0 + i) << 7) + x;
    const ushort4 ob = make_ushort4(f2bf(o.x), f2bf(o.y), f2bf(o.z), f2bf(o.w));
    if (c4 < 96) *(ushort4*)&qk[(size_t)p * 384 + c4 * 4] = ob;
    else         *(ushort4*)&vh[(size_t)p * 192 + (c4 - 96) * 4] = ob;
    if (i < TY - 1) {
#pragma unroll
      for (int j = 0; j < 3; ++j) { r0[j] = r1[j]; r1[j] = r2[j]; r2[j] = rn[j]; }
    }
  }
}

// ------- Gram v4 (MFMA, single-pass bf16): G = Q^T K per (img,h); + ssq -----
// qk bf16 [npix][384]: q = cols 0..191, k = cols 192..383.
// LDS: u32-packed PAIRS of channels, [128 rows][W=50]: q uints 0..23, k 24..47.
__global__ __launch_bounds__(256) void gram48_v4(const unsigned short* __restrict__ qk,
                                                 float* __restrict__ G,
                                                 float* __restrict__ ssqq,
                                                 float* __restrict__ ssqk) {
  constexpr int W = 50;
  __shared__ unsigned int smem[9216];   // staging uses 128*50=6400; reduce uses 9216
  const int tid = threadIdx.x;
  const int lane = tid & 63;
  const int wv = tid >> 6;
  const int pair = blockIdx.y;          // img*4 + h
  const int img = pair >> 2, h = pair & 3;

  f32x4 acc[3][3] = {};
  float ssq_acc = 0.f;
  const int sch = tid % 96;
  const int shalf = tid / 96;

  for (int rnd = 0; rnd < 2; ++rnd) {
    const int sbase = (img << 14) + blockIdx.x * 256 + rnd * 128;
#pragma unroll
    for (int r = 0; r < 6; ++r) {
      const int idx = tid + (r << 8);    // 0..1535 = 128 rows x 12 uint4
      const int row = idx / 12, part = idx % 12;
      const bool isq = part < 6;
      const int sub = isq ? part : part - 6;
      const uint4 v = *(const uint4*)&qk[(size_t)(sbase + row) * 384 + (isq ? 0 : 192) + h * 48 + sub * 8];
      *(uint4*)&smem[row * W + (isq ? 0 : 24) + sub * 4] = v;
    }
    __syncthreads();
    {
      const int s0 = wv * 32 + ((lane >> 4) << 3);
      const int cm = lane & 15;
      const int half = cm & 1;
      bf16x8 qf[3], kf[3];
#pragma unroll
      for (int t3 = 0; t3 < 3; ++t3) {
        const int qc = t3 * 8 + (cm >> 1);
#pragma unroll
        for (int j = 0; j < 8; ++j) {
          const unsigned uq = smem[(s0 + j) * W + qc];
          const unsigned uk = smem[(s0 + j) * W + 24 + qc];
          qf[t3][j] = (short)(half ? (uq >> 16) : (uq & 0xffffu));
          kf[t3][j] = (short)(half ? (uk >> 16) : (uk & 0xffffu));
        }
      }
#pragma unroll
      for (int mt = 0; mt < 3; ++mt)
#pragma unroll
        for (int nt = 0; nt < 3; ++nt)
          acc[mt][nt] = __builtin_amdgcn_mfma_f32_16x16x32_bf16(qf[mt], kf[nt], acc[mt][nt], 0, 0, 0);
    }
    if (tid < 192) {
      const int cu = (sch < 48) ? (sch >> 1) : 24 + ((sch - 48) >> 1);
      const int hf = sch & 1;
      const int sstart = shalf * 64;
#pragma unroll 4
      for (int s = 0; s < 64; ++s) {
        const unsigned u = smem[(sstart + s) * W + cu];
        const float v = bf2f((unsigned short)(hf ? (u >> 16) : (u & 0xffffu)));
        ssq_acc += v * v;
      }
    }
    __syncthreads();
  }

  // block reduce 4 wave-partials (reuse smem as floats), then atomics
  float* red = (float*)smem;
  const int col = lane & 15;
  const int rbase = (lane >> 4) * 4;
#pragma unroll
  for (int mt = 0; mt < 3; ++mt)
#pragma unroll
    for (int nt = 0; nt < 3; ++nt)
#pragma unroll
      for (int rg = 0; rg < 4; ++rg)
        red[wv * 2304 + (mt * 16 + rbase + rg) * 48 + nt * 16 + col] = acc[mt][nt][rg];
  __syncthreads();
  float* Gm = &G[(size_t)pair * 2304];
#pragma unroll
  for (int c = 0; c < 9; ++c) {
    const int cell = tid + (c << 8);
    const float s4 = red[cell] + red[2304 + cell] + red[4608 + cell] + red[6912 + cell];
    atomicAdd(&Gm[cell], s4);
  }
  if (tid < 192) {
    if (sch < 48) atomicAdd(&ssqq[img * 192 + h * 48 + sch], ssq_acc);
    else          atomicAdd(&ssqk[img * 192 + h * 48 + sch - 48], ssq_acc);
  }
}

// ---- softmax over d of G*temp/(|q||k|), one wave per (img,h,row) -----------
__global__ __launch_bounds__(64) void attn_softmax(const float* __restrict__ G,
                                                   const float* __restrict__ ssqq,
                                                   const float* __restrict__ ssqk,
                                                   const float* __restrict__ temp,
                                                   float* __restrict__ attn) {
  const int r = blockIdx.x;          // 0..47
  const int h = blockIdx.y & 3;
  const int img = blockIdx.y >> 2;
  const int lane = threadIdx.x;
  const size_t base = (size_t)(img * 4 + h) * 2304;
  const float t = temp[h];
  const float qn = ssqq[img * 192 + h * CH + r];
  float val = -1e30f;
  if (lane < 48) {
    const float kn = ssqk[img * 192 + h * CH + lane];
    val = G[base + r * 48 + lane] * t * rsqrtf(qn * kn);
  }
  float m = val;
#pragma unroll
  for (int off = 32; off; off >>= 1) m = fmaxf(m, __shfl_xor(m, off));
  const float e = (lane < 48) ? expf(val - m) : 0.f;
  float ssum = e;
#pragma unroll
  for (int off = 32; off; off >>= 1) ssum += __shfl_xor(ssum, off);
  if (lane < 48) attn[base + r * 48 + lane] = e / ssum;
}

// ---- W_eff^T[img][n][D] = sum_c' A[img][h(D)][c'][D%48] * Wp[48h+c'][n] ----
__global__ __launch_bounds__(256) void make_weff(const float* __restrict__ attn,
                                                 const float* __restrict__ wproj,
                                                 unsigned short* __restrict__ weh,
                                                 unsigned short* __restrict__ wel) {
  const int t = blockIdx.x * 256 + threadIdx.x;   // over 4*192*192
  const int img = t / 36864;
  const int r = t % 36864;
  const int n = r / 192;
  const int D = r % 192;
  const int h = D / 48, dd = D % 48;
  const float* A = &attn[(size_t)(img * 4 + h) * 2304 + dd];
  const float* Wp = &wproj[(size_t)(h * 48) * 192 + n];
  float acc = 0.f;
#pragma unroll
  for (int c = 0; c < 48; ++c) acc += A[c * 48] * Wp[c * 192];
  const unsigned short hb = f2bf(acc);
  weh[(size_t)img * 36864 + n * 192 + D] = hb;
  wel[(size_t)img * 36864 + n * 192 + D] = f2bf(acc - bf2f(hb));
}

}  // namespace

extern "C" void kernel_launch(void* const* d_in, const int* in_sizes, int n_in,
                              void* d_out, int out_size, void* d_ws, size_t ws_size,
                              hipStream_t stream) {
  const float* x      = (const float*)d_in[0];
  const float* w_qkv  = (const float*)d_in[1];
  const float* w_dw   = (const float*)d_in[2];
  const float* w_proj = (const float*)d_in[3];
  const float* temp   = (const float*)d_in[4];
  float* out = (float*)d_out;

  // NI images per pass. NI=4 ≈ 128 MB, fits the 256 MiB ws.
  auto layout_bytes = [](int NI) -> size_t {
    return (size_t)NI * HW * 576 * 2       // qkv bf16
         + (size_t)NI * HW * 384 * 2       // qk bf16
         + (size_t)NI * HW * 192 * 2       // vh (bf16)
         + 2 * 221184                      // wqh, wql
         + 153600                          // G, ssqq, ssqk (all 4 images)
         + 147456                          // attnb (all 4 images)
         + 2 * 294912;                     // weh, wel (all 4 images)
  };
  const int NI = (ws_size >= layout_bytes(4)) ? 4 : ((ws_size >= layout_bytes(2)) ? 2 : 1);
  const int npass = 4 / NI;
  const int npix = NI * HW;

  char* p = (char*)d_ws;
  unsigned short* qkv = (unsigned short*)p; p += (size_t)npix * 576 * 2;
  unsigned short* qk = (unsigned short*)p;  p += (size_t)npix * 384 * 2;
  unsigned short* vh = (unsigned short*)p;  p += (size_t)npix * 192 * 2;
  unsigned short* wqh = (unsigned short*)p; p += 221184;
  unsigned short* wql = (unsigned short*)p; p += 221184;
  float* G    = (float*)p;           p += 147456;   // 16 (img,h) pairs
  float* ssqq = (float*)p;           p += 3072;     // 4 img x 192
  float* ssqk = (float*)p;           p += 3072;
  float* attnb = (float*)p;          p += 147456;
  unsigned short* weh = (unsigned short*)p; p += 294912;
  unsigned short* wel = (unsigned short*)p;

  cvt_wqkv<<<432, 256, 0, stream>>>(w_qkv, wqh, wql);
  hipMemsetAsync(G, 0, 153600, stream);  // G+ssqq+ssqk, all 4 images, once

  for (int pass = 0; pass < npass; ++pass) {
    const float* xb = x + (size_t)pass * npix * K;
    float* outb = out + (size_t)pass * npix * C;
    float* Gp    = G + (size_t)pass * NI * 4 * 2304;
    float* sqp   = ssqq + (size_t)pass * NI * 192;
    float* skp   = ssqk + (size_t)pass * NI * 192;
    float* ap    = attnb + (size_t)pass * NI * 4 * 2304;
    unsigned short* wehp = weh + (size_t)pass * NI * 36864;
    unsigned short* welp = wel + (size_t)pass * NI * 36864;
    gemm_mfma<9, false, true, true><<<npix / 64, 256, 0, stream>>>(
        xb, wqh, wql, qkv);
    dwconv3x3_v5<<<npix * 144 / TY / 256, 256, 0, stream>>>(qkv, w_dw, qk, vh);
    gram48_v4<<<dim3(64, 4 * NI), 256, 0, stream>>>(qk, Gp, sqp, skp);
    attn_softmax<<<dim3(48, 4 * NI), 64, 0, stream>>>(Gp, sqp, skp, temp, ap);
    make_weff<<<NI * 144, 256, 0, stream>>>(ap, w_proj, wehp, welp);
    gemm_mfma<3, true, false, false><<<npix / 64, 256, 0, stream>>>(
        vh, wehp, welp, outb);
  }
}

// Round 17
// 133.567 us; speedup vs baseline: 1.7128x; 1.7128x over previous
//
#include <hip/hip_runtime.h>

namespace {

constexpr int HW = 16384;   // pixels per image
constexpr int C  = 192;
constexpr int C3 = 576;
constexpr int CH = 48;
constexpr int K  = 192;

using bf16x8 = __attribute__((ext_vector_type(8))) short;
using f32x4  = __attribute__((ext_vector_type(4))) float;

__device__ inline unsigned short f2bf(float f) {
  unsigned u = __float_as_uint(f);
  unsigned r = (u + 0x7fff + ((u >> 16) & 1)) >> 16;
  return (unsigned short)r;
}
__device__ inline float bf2f(unsigned short b) {
  return __uint_as_float(((unsigned)b) << 16);
}
__device__ inline float4 ld_bf4(const unsigned short* p) {
  const ushort4 u = *(const ushort4*)p;
  return make_float4(bf2f(u.x), bf2f(u.y), bf2f(u.z), bf2f(u.w));
}

// async global->LDS, 16B per lane. LDS dest = wave-uniform base + lane*16.
__device__ __forceinline__ void ld_g2l16(const unsigned short* g, unsigned short* l) {
  __builtin_amdgcn_global_load_lds(
      (const __attribute__((address_space(1))) unsigned int*)(unsigned long long)(const void*)g,
      (__attribute__((address_space(3))) unsigned int*)(unsigned int)(unsigned long long)(void*)l,
      16, 0, 0);
}

// ---- transpose + split qkv weights: [192,576] -> hi/lo [576][192] ----------
__global__ __launch_bounds__(256) void cvt_wqkv(const float* __restrict__ wqkv,
                                                unsigned short* __restrict__ wqh,
                                                unsigned short* __restrict__ wql) {
  const int t = blockIdx.x * 256 + threadIdx.x;  // 0 .. 576*192-1
  const int n = t / 192;
  const int k = t % 192;
  const float v = wqkv[k * C3 + n];
  const unsigned short h = f2bf(v);
  wqh[n * 192 + k] = h;
  wql[n * 192 + k] = f2bf(v - bf2f(h));
}

// ---- MFMA GEMM: Co[M, NT*64] = A[M,192] @ (Bh+Bl)[NT*64,192]^T, 2-pass -----
// Round-13 structure (block = 128 rows x ALL n-tiles, A in registers) with ONE
// change: B staged 2 k-steps per barrier (KB=64) -> 27 drains/block vs 54.
// CVTA: A fp32 -> rne bf16 during staging (padded LDS stride 40).
template <int NT, bool PERB, bool OBF16, bool CVTA>
__global__ __launch_bounds__(256) void gemm_mfma(const void* __restrict__ Ap,
                                                 const unsigned short* __restrict__ Bh,
                                                 const unsigned short* __restrict__ Bl,
                                                 void* __restrict__ Co) {
  constexpr int N = NT * 64;
  constexpr int AST = CVTA ? 40 : 32;   // A LDS row stride (ushorts)
  __shared__ __align__(16) unsigned short sA[128 * AST];
  __shared__ __align__(16) unsigned short sBh[2][2][64 * 32];
  __shared__ __align__(16) unsigned short sBl[2][2][64 * 32];
  const int t = threadIdx.x;
  const int lane = t & 63;
  const int wv = t >> 6;
  const int m0 = blockIdx.x * 128;
  const size_t boff = PERB ? (size_t)(m0 >> 14) * (192 * 192) : 0;
  const int wr = wv >> 1, wc = wv & 1;
  const int fr_row = lane & 15;
  const int fr_swz = ((lane >> 4) ^ (lane & 3)) << 3;
  const int arow0 = wv * 32;           // A staging rows per wave (2 issues x 16)
  const int lrow  = lane >> 2;
  const int lslot = lane & 3;
  const int brow0 = wv * 16;           // B staging rows per wave (1 issue)
  const int ssl   = lslot ^ (lrow & 3);  // stage-side slot (row mod 4)

  // ---- phase 1: A -> registers, staged k-step by k-step (round-13 exact) ---
  bf16x8 fah[6][4];
#pragma unroll
  for (int ks = 0; ks < 6; ++ks) {
    const int k0 = ks * 32;
#pragma unroll
    for (int r = 0; r < 2; ++r) {
      const int row = arow0 + r * 16 + lrow;
      if constexpr (CVTA) {
        const float* src = &((const float*)Ap)[(size_t)(m0 + row) * K + k0 + (lslot << 3)];
        const float4 f0 = *(const float4*)src;
        const float4 f1 = *(const float4*)(src + 4);
        bf16x8 h;
        h[0] = (short)f2bf(f0.x); h[1] = (short)f2bf(f0.y);
        h[2] = (short)f2bf(f0.z); h[3] = (short)f2bf(f0.w);
        h[4] = (short)f2bf(f1.x); h[5] = (short)f2bf(f1.y);
        h[6] = (short)f2bf(f1.z); h[7] = (short)f2bf(f1.w);
        const int sphys = lslot ^ (row & 3);
        *(bf16x8*)&sA[row * AST + (sphys << 3)] = h;
      } else {
        const size_t go = (size_t)(m0 + row) * K + k0 + ((lslot ^ (row & 3)) << 3);
        ld_g2l16(&((const unsigned short*)Ap)[go], &sA[(arow0 + r * 16) * AST]);
      }
    }
    __syncthreads();
#pragma unroll
    for (int i = 0; i < 4; ++i) {
      const int row = wr * 64 + i * 16 + fr_row;
      fah[ks][i] = *(const bf16x8*)&sA[row * AST + fr_swz];
    }
    __syncthreads();
  }

  // ---- phase 2: n-tile loop, B double-buffered in 2-k-step batches ---------
  auto stageB = [&](int buf, int nt_, int kp_) {
#pragma unroll
    for (int s = 0; s < 2; ++s) {
      const size_t go = boff + (size_t)(nt_ * 64 + brow0 + lrow) * K
                      + kp_ * 64 + s * 32 + (ssl << 3);
      ld_g2l16(&Bh[go], &sBh[buf][s][brow0 * 32]);
      ld_g2l16(&Bl[go], &sBl[buf][s][brow0 * 32]);
    }
  };

  stageB(0, 0, 0);
  __syncthreads();
  const int er = (lane >> 4) << 2;  // C/D: col=lane&15, row=(lane>>4)*4+reg
  const int ec = lane & 15;
  for (int nt = 0; nt < NT; ++nt) {
    f32x4 acc[4][2] = {};
#pragma unroll
    for (int kp = 0; kp < 3; ++kp) {
      const int buf = (nt + kp) & 1;
      const bool last = (nt == NT - 1) && (kp == 2);
      if (!last) {
        if (kp < 2) stageB(buf ^ 1, nt, kp + 1);
        else        stageB(buf ^ 1, nt + 1, 0);
      }
#pragma unroll
      for (int sub = 0; sub < 2; ++sub) {
        const int ks = kp * 2 + sub;
        bf16x8 fbh[2], fbl[2];
#pragma unroll
        for (int j = 0; j < 2; ++j) {
          const int row = wc * 32 + j * 16 + fr_row;
          fbh[j] = *(const bf16x8*)&sBh[buf][sub][row * 32 + fr_swz];
          fbl[j] = *(const bf16x8*)&sBl[buf][sub][row * 32 + fr_swz];
        }
#pragma unroll
        for (int i = 0; i < 4; ++i)
#pragma unroll
          for (int j = 0; j < 2; ++j) {
            acc[i][j] = __builtin_amdgcn_mfma_f32_16x16x32_bf16(fah[ks][i], fbh[j], acc[i][j], 0, 0, 0);
            acc[i][j] = __builtin_amdgcn_mfma_f32_16x16x32_bf16(fah[ks][i], fbl[j], acc[i][j], 0, 0, 0);
          }
      }
      if (!last) __syncthreads();
    }
#pragma unroll
    for (int i = 0; i < 4; ++i)
#pragma unroll
      for (int j = 0; j < 2; ++j) {
        const size_t base = (size_t)(m0 + wr * 64 + i * 16 + er) * N + nt * 64 + wc * 32 + j * 16 + ec;
        if constexpr (OBF16) {
          unsigned short* cp = (unsigned short*)Co + base;
#pragma unroll
          for (int r = 0; r < 4; ++r) cp[(size_t)r * N] = f2bf(acc[i][j][r]);
        } else {
          float* cp = (float*)Co + base;
#pragma unroll
          for (int r = 0; r < 4; ++r) cp[(size_t)r * N] = acc[i][j][r];
        }
      }
  }
}

// ---- depthwise 3x3 SAME, rolling-window TY=8, bf16 in/out ------------------
// q,k -> bf16 qk[p][384]; v -> bf16 vh[p][192]
constexpr int TY = 8;
__global__ __launch_bounds__(256) void dwconv3x3_v5(const unsigned short* __restrict__ in,
                                                    const float* __restrict__ wdw,
                                                    unsigned short* __restrict__ qk,
                                                    unsigned short* __restrict__ vh) {
  const int t = blockIdx.x * 256 + threadIdx.x;
  const int c4 = t % 144;
  const int rest = t / 144;          // (img, ystrip, x)
  const int x = rest & 127;
  const int ys = (rest >> 7) & 15;   // 16 strips of TY=8
  const int img = rest >> 11;
  const int y0 = ys * TY;

  float4 wt[3][3];
#pragma unroll
  for (int i = 0; i < 3; ++i)
#pragma unroll
    for (int j = 0; j < 3; ++j)
      wt[i][j] = *(const float4*)&wdw[(size_t)(i * 3 + j) * C3 + c4 * 4];

  const bool xm = x > 0, xp = x < 127;
  const unsigned short* ibase = &in[((size_t)((img << 14) + x)) * C3 + c4 * 4];
  const float4 z4 = make_float4(0.f, 0.f, 0.f, 0.f);
  const ptrdiff_t dxm = xm ? -(ptrdiff_t)C3 : 0;   // clamped ptr + select-zero
  const ptrdiff_t dxp = xp ? (ptrdiff_t)C3 : 0;

  auto ldrow = [&](int yy, float4* r) {
    if ((unsigned)yy < 128u) {
      const unsigned short* rp = ibase + (size_t)yy * (128 * C3);
      float4 a = ld_bf4(rp + dxm);
      float4 m = ld_bf4(rp);
      float4 b = ld_bf4(rp + dxp);
      if (!xm) a = z4;
      if (!xp) b = z4;
      r[0] = a; r[1] = m; r[2] = b;
    } else {
      r[0] = z4; r[1] = z4; r[2] = z4;
    }
  };

  float4 r0[3], r1[3], r2[3], rn[3];
  ldrow(y0 - 1, r0);
  ldrow(y0, r1);
  ldrow(y0 + 1, r2);

#pragma unroll
  for (int i = 0; i < TY; ++i) {
    if (i < TY - 1) ldrow(y0 + i + 2, rn);  // prefetch overlaps compute below
    float4 o = z4;
#pragma unroll
    for (int j = 0; j < 3; ++j) {
      o.x += r0[j].x * wt[0][j].x; o.y += r0[j].y * wt[0][j].y;
      o.z += r0[j].z * wt[0][j].z; o.w += r0[j].w * wt[0][j].w;
      o.x += r1[j].x * wt[1][j].x; o.y += r1[j].y * wt[1][j].y;
      o.z += r1[j].z * wt[1][j].z; o.w += r1[j].w * wt[1][j].w;
      o.x += r2[j].x * wt[2][j].x; o.y += r2[j].y * wt[2][j].y;
      o.z += r2[j].z * wt[2][j].z; o.w += r2[j].w * wt[2][j].w;
    }
    const int p = (img << 14) + ((y0 + i) << 7) + x;
    const ushort4 ob = make_ushort4(f2bf(o.x), f2bf(o.y), f2bf(o.z), f2bf(o.w));
    if (c4 < 96) *(ushort4*)&qk[(size_t)p * 384 + c4 * 4] = ob;
    else         *(ushort4*)&vh[(size_t)p * 192 + (c4 - 96) * 4] = ob;
    if (i < TY - 1) {
#pragma unroll
      for (int j = 0; j < 3; ++j) { r0[j] = r1[j]; r1[j] = r2[j]; r2[j] = rn[j]; }
    }
  }
}

// ------- Gram v4 (MFMA, single-pass bf16): G = Q^T K per (img,h); + ssq -----
// qk bf16 [npix][384]: q = cols 0..191, k = cols 192..383.
// LDS: u32-packed PAIRS of channels, [128 rows][W=50]: q uints 0..23, k 24..47.
__global__ __launch_bounds__(256) void gram48_v4(const unsigned short* __restrict__ qk,
                                                 float* __restrict__ G,
                                                 float* __restrict__ ssqq,
                                                 float* __restrict__ ssqk) {
  constexpr int W = 50;
  __shared__ unsigned int smem[9216];   // staging uses 128*50=6400; reduce uses 9216
  const int tid = threadIdx.x;
  const int lane = tid & 63;
  const int wv = tid >> 6;
  const int pair = blockIdx.y;          // img*4 + h
  const int img = pair >> 2, h = pair & 3;

  f32x4 acc[3][3] = {};
  float ssq_acc = 0.f;
  const int sch = tid % 96;
  const int shalf = tid / 96;

  for (int rnd = 0; rnd < 2; ++rnd) {
    const int sbase = (img << 14) + blockIdx.x * 256 + rnd * 128;
#pragma unroll
    for (int r = 0; r < 6; ++r) {
      const int idx = tid + (r << 8);    // 0..1535 = 128 rows x 12 uint4
      const int row = idx / 12, part = idx % 12;
      const bool isq = part < 6;
      const int sub = isq ? part : part - 6;
      const uint4 v = *(const uint4*)&qk[(size_t)(sbase + row) * 384 + (isq ? 0 : 192) + h * 48 + sub * 8];
      *(uint4*)&smem[row * W + (isq ? 0 : 24) + sub * 4] = v;
    }
    __syncthreads();
    {
      const int s0 = wv * 32 + ((lane >> 4) << 3);
      const int cm = lane & 15;
      const int half = cm & 1;
      bf16x8 qf[3], kf[3];
#pragma unroll
      for (int t3 = 0; t3 < 3; ++t3) {
        const int qc = t3 * 8 + (cm >> 1);
#pragma unroll
        for (int j = 0; j < 8; ++j) {
          const unsigned uq = smem[(s0 + j) * W + qc];
          const unsigned uk = smem[(s0 + j) * W + 24 + qc];
          qf[t3][j] = (short)(half ? (uq >> 16) : (uq & 0xffffu));
          kf[t3][j] = (short)(half ? (uk >> 16) : (uk & 0xffffu));
        }
      }
#pragma unroll
      for (int mt = 0; mt < 3; ++mt)
#pragma unroll
        for (int nt = 0; nt < 3; ++nt)
          acc[mt][nt] = __builtin_amdgcn_mfma_f32_16x16x32_bf16(qf[mt], kf[nt], acc[mt][nt], 0, 0, 0);
    }
    if (tid < 192) {
      const int cu = (sch < 48) ? (sch >> 1) : 24 + ((sch - 48) >> 1);
      const int hf = sch & 1;
      const int sstart = shalf * 64;
#pragma unroll 4
      for (int s = 0; s < 64; ++s) {
        const unsigned u = smem[(sstart + s) * W + cu];
        const float v = bf2f((unsigned short)(hf ? (u >> 16) : (u & 0xffffu)));
        ssq_acc += v * v;
      }
    }
    __syncthreads();
  }

  // block reduce 4 wave-partials (reuse smem as floats), then atomics
  float* red = (float*)smem;
  const int col = lane & 15;
  const int rbase = (lane >> 4) * 4;
#pragma unroll
  for (int mt = 0; mt < 3; ++mt)
#pragma unroll
    for (int nt = 0; nt < 3; ++nt)
#pragma unroll
      for (int rg = 0; rg < 4; ++rg)
        red[wv * 2304 + (mt * 16 + rbase + rg) * 48 + nt * 16 + col] = acc[mt][nt][rg];
  __syncthreads();
  float* Gm = &G[(size_t)pair * 2304];
#pragma unroll
  for (int c = 0; c < 9; ++c) {
    const int cell = tid + (c << 8);
    const float s4 = red[cell] + red[2304 + cell] + red[4608 + cell] + red[6912 + cell];
    atomicAdd(&Gm[cell], s4);
  }
  if (tid < 192) {
    if (sch < 48) atomicAdd(&ssqq[img * 192 + h * 48 + sch], ssq_acc);
    else          atomicAdd(&ssqk[img * 192 + h * 48 + sch - 48], ssq_acc);
  }
}

// ---- softmax over d of G*temp/(|q||k|), one wave per (img,h,row) -----------
__global__ __launch_bounds__(64) void attn_softmax(const float* __restrict__ G,
                                                   const float* __restrict__ ssqq,
                                                   const float* __restrict__ ssqk,
                                                   const float* __restrict__ temp,
                                                   float* __restrict__ attn) {
  const int r = blockIdx.x;          // 0..47
  const int h = blockIdx.y & 3;
  const int img = blockIdx.y >> 2;
  const int lane = threadIdx.x;
  const size_t base = (size_t)(img * 4 + h) * 2304;
  const float t = temp[h];
  const float qn = ssqq[img * 192 + h * CH + r];
  float val = -1e30f;
  if (lane < 48) {
    const float kn = ssqk[img * 192 + h * CH + lane];
    val = G[base + r * 48 + lane] * t * rsqrtf(qn * kn);
  }
  float m = val;
#pragma unroll
  for (int off = 32; off; off >>= 1) m = fmaxf(m, __shfl_xor(m, off));
  const float e = (lane < 48) ? expf(val - m) : 0.f;
  float ssum = e;
#pragma unroll
  for (int off = 32; off; off >>= 1) ssum += __shfl_xor(ssum, off);
  if (lane < 48) attn[base + r * 48 + lane] = e / ssum;
}

// ---- W_eff^T[img][n][D] = sum_c' A[img][h(D)][c'][D%48] * Wp[48h+c'][n] ----
__global__ __launch_bounds__(256) void make_weff(const float* __restrict__ attn,
                                                 const float* __restrict__ wproj,
                                                 unsigned short* __restrict__ weh,
                                                 unsigned short* __restrict__ wel) {
  const int t = blockIdx.x * 256 + threadIdx.x;   // over 4*192*192
  const int img = t / 36864;
  const int r = t % 36864;
  const int n = r / 192;
  const int D = r % 192;
  const int h = D / 48, dd = D % 48;
  const float* A = &attn[(size_t)(img * 4 + h) * 2304 + dd];
  const float* Wp = &wproj[(size_t)(h * 48) * 192 + n];
  float acc = 0.f;
#pragma unroll
  for (int c = 0; c < 48; ++c) acc += A[c * 48] * Wp[c * 192];
  const unsigned short hb = f2bf(acc);
  weh[(size_t)img * 36864 + n * 192 + D] = hb;
  wel[(size_t)img * 36864 + n * 192 + D] = f2bf(acc - bf2f(hb));
}

}  // namespace

extern "C" void kernel_launch(void* const* d_in, const int* in_sizes, int n_in,
                              void* d_out, int out_size, void* d_ws, size_t ws_size,
                              hipStream_t stream) {
  const float* x      = (const float*)d_in[0];
  const float* w_qkv  = (const float*)d_in[1];
  const float* w_dw   = (const float*)d_in[2];
  const float* w_proj = (const float*)d_in[3];
  const float* temp   = (const float*)d_in[4];
  float* out = (float*)d_out;

  // NI images per pass. NI=4 ≈ 128 MB, fits the 256 MiB ws.
  auto layout_bytes = [](int NI) -> size_t {
    return (size_t)NI * HW * 576 * 2       // qkv bf16
         + (size_t)NI * HW * 384 * 2       // qk bf16
         + (size_t)NI * HW * 192 * 2       // vh (bf16)
         + 2 * 221184                      // wqh, wql
         + 153600                          // G, ssqq, ssqk (all 4 images)
         + 147456                          // attnb (all 4 images)
         + 2 * 294912;                     // weh, wel (all 4 images)
  };
  const int NI = (ws_size >= layout_bytes(4)) ? 4 : ((ws_size >= layout_bytes(2)) ? 2 : 1);
  const int npass = 4 / NI;
  const int npix = NI * HW;

  char* p = (char*)d_ws;
  unsigned short* qkv = (unsigned short*)p; p += (size_t)npix * 576 * 2;
  unsigned short* qk = (unsigned short*)p;  p += (size_t)npix * 384 * 2;
  unsigned short* vh = (unsigned short*)p;  p += (size_t)npix * 192 * 2;
  unsigned short* wqh = (unsigned short*)p; p += 221184;
  unsigned short* wql = (unsigned short*)p; p += 221184;
  float* G    = (float*)p;           p += 147456;   // 16 (img,h) pairs
  float* ssqq = (float*)p;           p += 3072;     // 4 img x 192
  float* ssqk = (float*)p;           p += 3072;
  float* attnb = (float*)p;          p += 147456;
  unsigned short* weh = (unsigned short*)p; p += 294912;
  unsigned short* wel = (unsigned short*)p;

  cvt_wqkv<<<432, 256, 0, stream>>>(w_qkv, wqh, wql);
  hipMemsetAsync(G, 0, 153600, stream);  // G+ssqq+ssqk, all 4 images, once

  for (int pass = 0; pass < npass; ++pass) {
    const float* xb = x + (size_t)pass * npix * K;
    float* outb = out + (size_t)pass * npix * C;
    float* Gp    = G + (size_t)pass * NI * 4 * 2304;
    float* sqp   = ssqq + (size_t)pass * NI * 192;
    float* skp   = ssqk + (size_t)pass * NI * 192;
    float* ap    = attnb + (size_t)pass * NI * 4 * 2304;
    unsigned short* wehp = weh + (size_t)pass * NI * 36864;
    unsigned short* welp = wel + (size_t)pass * NI * 36864;
    gemm_mfma<9, false, true, true><<<npix / 128, 256, 0, stream>>>(
        xb, wqh, wql, qkv);
    dwconv3x3_v5<<<npix * 144 / TY / 256, 256, 0, stream>>>(qkv, w_dw, qk, vh);
    gram48_v4<<<dim3(64, 4 * NI), 256, 0, stream>>>(qk, Gp, sqp, skp);
    attn_softmax<<<dim3(48, 4 * NI), 64, 0, stream>>>(Gp, sqp, skp, temp, ap);
    make_weff<<<NI * 144, 256, 0, stream>>>(ap, w_proj, wehp, welp);
    gemm_mfma<3, true, false, false><<<npix / 128, 256, 0, stream>>>(
        vh, wehp, welp, outb);
  }
}

// Round 18
// 127.504 us; speedup vs baseline: 1.7943x; 1.0475x over previous
//
#include <hip/hip_runtime.h>

namespace {

constexpr int HW = 16384;   // pixels per image
constexpr int C  = 192;
constexpr int C3 = 576;
constexpr int CH = 48;
constexpr int K  = 192;

using bf16x8 = __attribute__((ext_vector_type(8))) short;
using f32x4  = __attribute__((ext_vector_type(4))) float;

__device__ inline unsigned short f2bf(float f) {
  unsigned u = __float_as_uint(f);
  unsigned r = (u + 0x7fff + ((u >> 16) & 1)) >> 16;
  return (unsigned short)r;
}
__device__ inline float bf2f(unsigned short b) {
  return __uint_as_float(((unsigned)b) << 16);
}
__device__ inline float4 ld_bf4(const unsigned short* p) {
  const ushort4 u = *(const ushort4*)p;
  return make_float4(bf2f(u.x), bf2f(u.y), bf2f(u.z), bf2f(u.w));
}

// async global->LDS, 16B per lane. LDS dest = wave-uniform base + lane*16.
__device__ __forceinline__ void ld_g2l16(const unsigned short* g, unsigned short* l) {
  __builtin_amdgcn_global_load_lds(
      (const __attribute__((address_space(1))) unsigned int*)(unsigned long long)(const void*)g,
      (__attribute__((address_space(3))) unsigned int*)(unsigned int)(unsigned long long)(void*)l,
      16, 0, 0);
}

// ---- transpose qkv weights: [192,576] -> bf16 [576][192] (hi only) ---------
__global__ __launch_bounds__(256) void cvt_wqkv(const float* __restrict__ wqkv,
                                                unsigned short* __restrict__ wqh) {
  const int t = blockIdx.x * 256 + threadIdx.x;  // 0 .. 576*192-1
  const int n = t / 192;
  const int k = t % 192;
  wqh[n * 192 + k] = f2bf(wqkv[k * C3 + n]);
}

// ---- MFMA GEMM: Co[M, NT*64] = A[M,192] @ B[NT*64,192]^T -------------------
// Round-17 structure (block = 128 rows x ALL n-tiles, A in registers, B staged
// 2 k-steps per barrier). TWOB: B = Bh + Bl (2-pass Markidis); else Bh only.
// CVTA: A fp32 -> rne bf16 during staging (padded LDS stride 40).
template <int NT, bool PERB, bool OBF16, bool CVTA, bool TWOB>
__global__ __launch_bounds__(256) void gemm_mfma(const void* __restrict__ Ap,
                                                 const unsigned short* __restrict__ Bh,
                                                 const unsigned short* __restrict__ Bl,
                                                 void* __restrict__ Co) {
  constexpr int N = NT * 64;
  constexpr int AST = CVTA ? 40 : 32;   // A LDS row stride (ushorts)
  __shared__ __align__(16) unsigned short sA[128 * AST];
  __shared__ __align__(16) unsigned short sBh[2][2][64 * 32];
  __shared__ __align__(16) unsigned short sBl[TWOB ? 2 : 1][TWOB ? 2 : 1][TWOB ? 64 * 32 : 8];
  const int t = threadIdx.x;
  const int lane = t & 63;
  const int wv = t >> 6;
  const int m0 = blockIdx.x * 128;
  const size_t boff = PERB ? (size_t)(m0 >> 14) * (192 * 192) : 0;
  const int wr = wv >> 1, wc = wv & 1;
  const int fr_row = lane & 15;
  const int fr_swz = ((lane >> 4) ^ (lane & 3)) << 3;
  const int arow0 = wv * 32;           // A staging rows per wave (2 issues x 16)
  const int lrow  = lane >> 2;
  const int lslot = lane & 3;
  const int brow0 = wv * 16;           // B staging rows per wave (1 issue)
  const int ssl   = lslot ^ (lrow & 3);  // stage-side slot (row mod 4)

  // ---- phase 1: A -> registers, staged k-step by k-step --------------------
  bf16x8 fah[6][4];
#pragma unroll
  for (int ks = 0; ks < 6; ++ks) {
    const int k0 = ks * 32;
#pragma unroll
    for (int r = 0; r < 2; ++r) {
      const int row = arow0 + r * 16 + lrow;
      if constexpr (CVTA) {
        const float* src = &((const float*)Ap)[(size_t)(m0 + row) * K + k0 + (lslot << 3)];
        const float4 f0 = *(const float4*)src;
        const float4 f1 = *(const float4*)(src + 4);
        bf16x8 h;
        h[0] = (short)f2bf(f0.x); h[1] = (short)f2bf(f0.y);
        h[2] = (short)f2bf(f0.z); h[3] = (short)f2bf(f0.w);
        h[4] = (short)f2bf(f1.x); h[5] = (short)f2bf(f1.y);
        h[6] = (short)f2bf(f1.z); h[7] = (short)f2bf(f1.w);
        const int sphys = lslot ^ (row & 3);
        *(bf16x8*)&sA[row * AST + (sphys << 3)] = h;
      } else {
        const size_t go = (size_t)(m0 + row) * K + k0 + ((lslot ^ (row & 3)) << 3);
        ld_g2l16(&((const unsigned short*)Ap)[go], &sA[(arow0 + r * 16) * AST]);
      }
    }
    __syncthreads();
#pragma unroll
    for (int i = 0; i < 4; ++i) {
      const int row = wr * 64 + i * 16 + fr_row;
      fah[ks][i] = *(const bf16x8*)&sA[row * AST + fr_swz];
    }
    __syncthreads();
  }

  // ---- phase 2: n-tile loop, B double-buffered in 2-k-step batches ---------
  auto stageB = [&](int buf, int nt_, int kp_) {
#pragma unroll
    for (int s = 0; s < 2; ++s) {
      const size_t go = boff + (size_t)(nt_ * 64 + brow0 + lrow) * K
                      + kp_ * 64 + s * 32 + (ssl << 3);
      ld_g2l16(&Bh[go], &sBh[buf][s][brow0 * 32]);
      if constexpr (TWOB) ld_g2l16(&Bl[go], &sBl[buf][s][brow0 * 32]);
    }
  };

  stageB(0, 0, 0);
  __syncthreads();
  const int er = (lane >> 4) << 2;  // C/D: col=lane&15, row=(lane>>4)*4+reg
  const int ec = lane & 15;
  for (int nt = 0; nt < NT; ++nt) {
    f32x4 acc[4][2] = {};
#pragma unroll
    for (int kp = 0; kp < 3; ++kp) {
      const int buf = (nt + kp) & 1;
      const bool last = (nt == NT - 1) && (kp == 2);
      if (!last) {
        if (kp < 2) stageB(buf ^ 1, nt, kp + 1);
        else        stageB(buf ^ 1, nt + 1, 0);
      }
#pragma unroll
      for (int sub = 0; sub < 2; ++sub) {
        const int ks = kp * 2 + sub;
        bf16x8 fbh[2];
#pragma unroll
        for (int j = 0; j < 2; ++j) {
          const int row = wc * 32 + j * 16 + fr_row;
          fbh[j] = *(const bf16x8*)&sBh[buf][sub][row * 32 + fr_swz];
        }
#pragma unroll
        for (int i = 0; i < 4; ++i)
#pragma unroll
          for (int j = 0; j < 2; ++j)
            acc[i][j] = __builtin_amdgcn_mfma_f32_16x16x32_bf16(fah[ks][i], fbh[j], acc[i][j], 0, 0, 0);
        if constexpr (TWOB) {
          bf16x8 fbl[2];
#pragma unroll
          for (int j = 0; j < 2; ++j) {
            const int row = wc * 32 + j * 16 + fr_row;
            fbl[j] = *(const bf16x8*)&sBl[buf][sub][row * 32 + fr_swz];
          }
#pragma unroll
          for (int i = 0; i < 4; ++i)
#pragma unroll
            for (int j = 0; j < 2; ++j)
              acc[i][j] = __builtin_amdgcn_mfma_f32_16x16x32_bf16(fah[ks][i], fbl[j], acc[i][j], 0, 0, 0);
        }
      }
      if (!last) __syncthreads();
    }
#pragma unroll
    for (int i = 0; i < 4; ++i)
#pragma unroll
      for (int j = 0; j < 2; ++j) {
        const size_t base = (size_t)(m0 + wr * 64 + i * 16 + er) * N + nt * 64 + wc * 32 + j * 16 + ec;
        if constexpr (OBF16) {
          unsigned short* cp = (unsigned short*)Co + base;
#pragma unroll
          for (int r = 0; r < 4; ++r) cp[(size_t)r * N] = f2bf(acc[i][j][r]);
        } else {
          float* cp = (float*)Co + base;
#pragma unroll
          for (int r = 0; r < 4; ++r) cp[(size_t)r * N] = acc[i][j][r];
        }
      }
  }
}

// ---- depthwise 3x3 SAME, rolling-window TY=8, bf16 in/out ------------------
// q,k -> bf16 qk[p][384]; v -> bf16 vh[p][192]
constexpr int TY = 8;
__global__ __launch_bounds__(256) void dwconv3x3_v5(const unsigned short* __restrict__ in,
                                                    const float* __restrict__ wdw,
                                                    unsigned short* __restrict__ qk,
                                                    unsigned short* __restrict__ vh) {
  const int t = blockIdx.x * 256 + threadIdx.x;
  const int c4 = t % 144;
  const int rest = t / 144;          // (img, ystrip, x)
  const int x = rest & 127;
  const int ys = (rest >> 7) & 15;   // 16 strips of TY=8
  const int img = rest >> 11;
  const int y0 = ys * TY;

  float4 wt[3][3];
#pragma unroll
  for (int i = 0; i < 3; ++i)
#pragma unroll
    for (int j = 0; j < 3; ++j)
      wt[i][j] = *(const float4*)&wdw[(size_t)(i * 3 + j) * C3 + c4 * 4];

  const bool xm = x > 0, xp = x < 127;
  const unsigned short* ibase = &in[((size_t)((img << 14) + x)) * C3 + c4 * 4];
  const float4 z4 = make_float4(0.f, 0.f, 0.f, 0.f);
  const ptrdiff_t dxm = xm ? -(ptrdiff_t)C3 : 0;   // clamped ptr + select-zero
  const ptrdiff_t dxp = xp ? (ptrdiff_t)C3 : 0;

  auto ldrow = [&](int yy, float4* r) {
    if ((unsigned)yy < 128u) {
      const unsigned short* rp = ibase + (size_t)yy * (128 * C3);
      float4 a = ld_bf4(rp + dxm);
      float4 m = ld_bf4(rp);
      float4 b = ld_bf4(rp + dxp);
      if (!xm) a = z4;
      if (!xp) b = z4;
      r[0] = a; r[1] = m; r[2] = b;
    } else {
      r[0] = z4; r[1] = z4; r[2] = z4;
    }
  };

  float4 r0[3], r1[3], r2[3], rn[3];
  ldrow(y0 - 1, r0);
  ldrow(y0, r1);
  ldrow(y0 + 1, r2);

#pragma unroll
  for (int i = 0; i < TY; ++i) {
    if (i < TY - 1) ldrow(y0 + i + 2, rn);  // prefetch overlaps compute below
    float4 o = z4;
#pragma unroll
    for (int j = 0; j < 3; ++j) {
      o.x += r0[j].x * wt[0][j].x; o.y += r0[j].y * wt[0][j].y;
      o.z += r0[j].z * wt[0][j].z; o.w += r0[j].w * wt[0][j].w;
      o.x += r1[j].x * wt[1][j].x; o.y += r1[j].y * wt[1][j].y;
      o.z += r1[j].z * wt[1][j].z; o.w += r1[j].w * wt[1][j].w;
      o.x += r2[j].x * wt[2][j].x; o.y += r2[j].y * wt[2][j].y;
      o.z += r2[j].z * wt[2][j].z; o.w += r2[j].w * wt[2][j].w;
    }
    const int p = (img << 14) + ((y0 + i) << 7) + x;
    const ushort4 ob = make_ushort4(f2bf(o.x), f2bf(o.y), f2bf(o.z), f2bf(o.w));
    if (c4 < 96) *(ushort4*)&qk[(size_t)p * 384 + c4 * 4] = ob;
    else         *(ushort4*)&vh[(size_t)p * 192 + (c4 - 96) * 4] = ob;
    if (i < TY - 1) {
#pragma unroll
      for (int j = 0; j < 3; ++j) { r0[j] = r1[j]; r1[j] = r2[j]; r2[j] = rn[j]; }
    }
  }
}

// ------- Gram v4 (MFMA, single-pass bf16): G = Q^T K per (img,h); + ssq -----
// qk bf16 [npix][384]: q = cols 0..191, k = cols 192..383.
// LDS: u32-packed PAIRS of channels, [128 rows][W=50]: q uints 0..23, k 24..47.
__global__ __launch_bounds__(256) void gram48_v4(const unsigned short* __restrict__ qk,
                                                 float* __restrict__ G,
                                                 float* __restrict__ ssqq,
                                                 float* __restrict__ ssqk) {
  constexpr int W = 50;
  __shared__ unsigned int smem[9216];   // staging uses 128*50=6400; reduce uses 9216
  const int tid = threadIdx.x;
  const int lane = tid & 63;
  const int wv = tid >> 6;
  const int pair = blockIdx.y;          // img*4 + h
  const int img = pair >> 2, h = pair & 3;

  f32x4 acc[3][3] = {};
  float ssq_acc = 0.f;
  const int sch = tid % 96;
  const int shalf = tid / 96;

  for (int rnd = 0; rnd < 2; ++rnd) {
    const int sbase = (img << 14) + blockIdx.x * 256 + rnd * 128;
#pragma unroll
    for (int r = 0; r < 6; ++r) {
      const int idx = tid + (r << 8);    // 0..1535 = 128 rows x 12 uint4
      const int row = idx / 12, part = idx % 12;
      const bool isq = part < 6;
      const int sub = isq ? part : part - 6;
      const uint4 v = *(const uint4*)&qk[(size_t)(sbase + row) * 384 + (isq ? 0 : 192) + h * 48 + sub * 8];
      *(uint4*)&smem[row * W + (isq ? 0 : 24) + sub * 4] = v;
    }
    __syncthreads();
    {
      const int s0 = wv * 32 + ((lane >> 4) << 3);
      const int cm = lane & 15;
      const int half = cm & 1;
      bf16x8 qf[3], kf[3];
#pragma unroll
      for (int t3 = 0; t3 < 3; ++t3) {
        const int qc = t3 * 8 + (cm >> 1);
#pragma unroll
        for (int j = 0; j < 8; ++j) {
          const unsigned uq = smem[(s0 + j) * W + qc];
          const unsigned uk = smem[(s0 + j) * W + 24 + qc];
          qf[t3][j] = (short)(half ? (uq >> 16) : (uq & 0xffffu));
          kf[t3][j] = (short)(half ? (uk >> 16) : (uk & 0xffffu));
        }
      }
#pragma unroll
      for (int mt = 0; mt < 3; ++mt)
#pragma unroll
        for (int nt = 0; nt < 3; ++nt)
          acc[mt][nt] = __builtin_amdgcn_mfma_f32_16x16x32_bf16(qf[mt], kf[nt], acc[mt][nt], 0, 0, 0);
    }
    if (tid < 192) {
      const int cu = (sch < 48) ? (sch >> 1) : 24 + ((sch - 48) >> 1);
      const int hf = sch & 1;
      const int sstart = shalf * 64;
#pragma unroll 4
      for (int s = 0; s < 64; ++s) {
        const unsigned u = smem[(sstart + s) * W + cu];
        const float v = bf2f((unsigned short)(hf ? (u >> 16) : (u & 0xffffu)));
        ssq_acc += v * v;
      }
    }
    __syncthreads();
  }

  // block reduce 4 wave-partials (reuse smem as floats), then atomics
  float* red = (float*)smem;
  const int col = lane & 15;
  const int rbase = (lane >> 4) * 4;
#pragma unroll
  for (int mt = 0; mt < 3; ++mt)
#pragma unroll
    for (int nt = 0; nt < 3; ++nt)
#pragma unroll
      for (int rg = 0; rg < 4; ++rg)
        red[wv * 2304 + (mt * 16 + rbase + rg) * 48 + nt * 16 + col] = acc[mt][nt][rg];
  __syncthreads();
  float* Gm = &G[(size_t)pair * 2304];
#pragma unroll
  for (int c = 0; c < 9; ++c) {
    const int cell = tid + (c << 8);
    const float s4 = red[cell] + red[2304 + cell] + red[4608 + cell] + red[6912 + cell];
    atomicAdd(&Gm[cell], s4);
  }
  if (tid < 192) {
    if (sch < 48) atomicAdd(&ssqq[img * 192 + h * 48 + sch], ssq_acc);
    else          atomicAdd(&ssqk[img * 192 + h * 48 + sch - 48], ssq_acc);
  }
}

// ---- softmax over d of G*temp/(|q||k|), one wave per (img,h,row) -----------
__global__ __launch_bounds__(64) void attn_softmax(const float* __restrict__ G,
                                                   const float* __restrict__ ssqq,
                                                   const float* __restrict__ ssqk,
                                                   const float* __restrict__ temp,
                                                   float* __restrict__ attn) {
  const int r = blockIdx.x;          // 0..47
  const int h = blockIdx.y & 3;
  const int img = blockIdx.y >> 2;
  const int lane = threadIdx.x;
  const size_t base = (size_t)(img * 4 + h) * 2304;
  const float t = temp[h];
  const float qn = ssqq[img * 192 + h * CH + r];
  float val = -1e30f;
  if (lane < 48) {
    const float kn = ssqk[img * 192 + h * CH + lane];
    val = G[base + r * 48 + lane] * t * rsqrtf(qn * kn);
  }
  float m = val;
#pragma unroll
  for (int off = 32; off; off >>= 1) m = fmaxf(m, __shfl_xor(m, off));
  const float e = (lane < 48) ? expf(val - m) : 0.f;
  float ssum = e;
#pragma unroll
  for (int off = 32; off; off >>= 1) ssum += __shfl_xor(ssum, off);
  if (lane < 48) attn[base + r * 48 + lane] = e / ssum;
}

// ---- W_eff^T[img][n][D] = sum_c' A[img][h(D)][c'][D%48] * Wp[48h+c'][n] ----
__global__ __launch_bounds__(256) void make_weff(const float* __restrict__ attn,
                                                 const float* __restrict__ wproj,
                                                 unsigned short* __restrict__ weh,
                                                 unsigned short* __restrict__ wel) {
  const int t = blockIdx.x * 256 + threadIdx.x;   // over 4*192*192
  const int img = t / 36864;
  const int r = t % 36864;
  const int n = r / 192;
  const int D = r % 192;
  const int h = D / 48, dd = D % 48;
  const float* A = &attn[(size_t)(img * 4 + h) * 2304 + dd];
  const float* Wp = &wproj[(size_t)(h * 48) * 192 + n];
  float acc = 0.f;
#pragma unroll
  for (int c = 0; c < 48; ++c) acc += A[c * 48] * Wp[c * 192];
  const unsigned short hb = f2bf(acc);
  weh[(size_t)img * 36864 + n * 192 + D] = hb;
  wel[(size_t)img * 36864 + n * 192 + D] = f2bf(acc - bf2f(hb));
}

}  // namespace

extern "C" void kernel_launch(void* const* d_in, const int* in_sizes, int n_in,
                              void* d_out, int out_size, void* d_ws, size_t ws_size,
                              hipStream_t stream) {
  const float* x      = (const float*)d_in[0];
  const float* w_qkv  = (const float*)d_in[1];
  const float* w_dw   = (const float*)d_in[2];
  const float* w_proj = (const float*)d_in[3];
  const float* temp   = (const float*)d_in[4];
  float* out = (float*)d_out;

  // NI images per pass. NI=4 ≈ 128 MB, fits the 256 MiB ws.
  auto layout_bytes = [](int NI) -> size_t {
    return (size_t)NI * HW * 576 * 2       // qkv bf16
         + (size_t)NI * HW * 384 * 2       // qk bf16
         + (size_t)NI * HW * 192 * 2       // vh (bf16)
         + 221184                          // wqh
         + 153600                          // G, ssqq, ssqk (all 4 images)
         + 147456                          // attnb (all 4 images)
         + 2 * 294912;                     // weh, wel (all 4 images)
  };
  const int NI = (ws_size >= layout_bytes(4)) ? 4 : ((ws_size >= layout_bytes(2)) ? 2 : 1);
  const int npass = 4 / NI;
  const int npix = NI * HW;

  char* p = (char*)d_ws;
  unsigned short* qkv = (unsigned short*)p; p += (size_t)npix * 576 * 2;
  unsigned short* qk = (unsigned short*)p;  p += (size_t)npix * 384 * 2;
  unsigned short* vh = (unsigned short*)p;  p += (size_t)npix * 192 * 2;
  unsigned short* wqh = (unsigned short*)p; p += 221184;
  float* G    = (float*)p;           p += 147456;   // 16 (img,h) pairs
  float* ssqq = (float*)p;           p += 3072;     // 4 img x 192
  float* ssqk = (float*)p;           p += 3072;
  float* attnb = (float*)p;          p += 147456;
  unsigned short* weh = (unsigned short*)p; p += 294912;
  unsigned short* wel = (unsigned short*)p;

  cvt_wqkv<<<432, 256, 0, stream>>>(w_qkv, wqh);
  hipMemsetAsync(G, 0, 153600, stream);  // G+ssqq+ssqk, all 4 images, once

  for (int pass = 0; pass < npass; ++pass) {
    const float* xb = x + (size_t)pass * npix * K;
    float* outb = out + (size_t)pass * npix * C;
    float* Gp    = G + (size_t)pass * NI * 4 * 2304;
    float* sqp   = ssqq + (size_t)pass * NI * 192;
    float* skp   = ssqk + (size_t)pass * NI * 192;
    float* ap    = attnb + (size_t)pass * NI * 4 * 2304;
    unsigned short* wehp = weh + (size_t)pass * NI * 36864;
    unsigned short* welp = wel + (size_t)pass * NI * 36864;
    gemm_mfma<9, false, true, true, false><<<npix / 128, 256, 0, stream>>>(
        xb, wqh, wqh, qkv);
    dwconv3x3_v5<<<npix * 144 / TY / 256, 256, 0, stream>>>(qkv, w_dw, qk, vh);
    gram48_v4<<<dim3(64, 4 * NI), 256, 0, stream>>>(qk, Gp, sqp, skp);
    attn_softmax<<<dim3(48, 4 * NI), 64, 0, stream>>>(Gp, sqp, skp, temp, ap);
    make_weff<<<NI * 144, 256, 0, stream>>>(ap, w_proj, wehp, welp);
    gemm_mfma<3, true, false, false, true><<<npix / 128, 256, 0, stream>>>(
        vh, wehp, welp, outb);
  }
}

// Round 19
// 122.242 us; speedup vs baseline: 1.8715x; 1.0430x over previous
//
#include <hip/hip_runtime.h>

namespace {

constexpr int HW = 16384;   // pixels per image
constexpr int C  = 192;
constexpr int C3 = 576;
constexpr int CH = 48;
constexpr int K  = 192;

using bf16x8 = __attribute__((ext_vector_type(8))) short;
using f32x4  = __attribute__((ext_vector_type(4))) float;

__device__ inline unsigned short f2bf(float f) {
  unsigned u = __float_as_uint(f);
  unsigned r = (u + 0x7fff + ((u >> 16) & 1)) >> 16;
  return (unsigned short)r;
}
__device__ inline float bf2f(unsigned short b) {
  return __uint_as_float(((unsigned)b) << 16);
}
__device__ inline float4 ld_bf4(const unsigned short* p) {
  const ushort4 u = *(const ushort4*)p;
  return make_float4(bf2f(u.x), bf2f(u.y), bf2f(u.z), bf2f(u.w));
}

// async global->LDS, 16B per lane. LDS dest = wave-uniform base + lane*16.
__device__ __forceinline__ void ld_g2l16(const unsigned short* g, unsigned short* l) {
  __builtin_amdgcn_global_load_lds(
      (const __attribute__((address_space(1))) unsigned int*)(unsigned long long)(const void*)g,
      (__attribute__((address_space(3))) unsigned int*)(unsigned int)(unsigned long long)(void*)l,
      16, 0, 0);
}

// ---- transpose qkv weights: [192,576] -> bf16 [576][192] (hi only) ---------
__global__ __launch_bounds__(256) void cvt_wqkv(const float* __restrict__ wqkv,
                                                unsigned short* __restrict__ wqh) {
  const int t = blockIdx.x * 256 + threadIdx.x;  // 0 .. 576*192-1
  const int n = t / 192;
  const int k = t % 192;
  wqh[n * 192 + k] = f2bf(wqkv[k * C3 + n]);
}

// ---- MFMA GEMM: Co[M, NT*64] = A[M,192] @ B[NT*64,192]^T (bf16 1-pass) -----
// Block = 128 rows x ALL n-tiles, A in registers (fah[6][4]).
// Phase 2: B staged a FULL n-tile ahead (sB[2][6]) -> one barrier per n-tile;
// stage->use distance = 48 MFMA, covering L2 latency (fixes r17's too-short
// distance). CVTA: A fp32 -> rne bf16 during staging (padded LDS stride 40).
template <int NT, bool PERB, bool OBF16, bool CVTA>
__global__ __launch_bounds__(256) void gemm_mfma(const void* __restrict__ Ap,
                                                 const unsigned short* __restrict__ Bh,
                                                 void* __restrict__ Co) {
  constexpr int N = NT * 64;
  constexpr int AST = CVTA ? 40 : 32;   // A LDS row stride (ushorts)
  __shared__ __align__(16) unsigned short sA[128 * AST];
  __shared__ __align__(16) unsigned short sB[2][6][64 * 32];
  const int t = threadIdx.x;
  const int lane = t & 63;
  const int wv = t >> 6;
  const int m0 = blockIdx.x * 128;
  const size_t boff = PERB ? (size_t)(m0 >> 14) * (192 * 192) : 0;
  const int wr = wv >> 1, wc = wv & 1;
  const int fr_row = lane & 15;
  const int fr_swz = ((lane >> 4) ^ (lane & 3)) << 3;
  const int arow0 = wv * 32;           // A staging rows per wave (2 issues x 16)
  const int lrow  = lane >> 2;
  const int lslot = lane & 3;
  const int brow0 = wv * 16;           // B staging rows per wave
  const int ssl   = lslot ^ (lrow & 3);  // stage-side slot (row mod 4)

  // ---- phase 1: A -> registers, staged k-step by k-step --------------------
  bf16x8 fah[6][4];
#pragma unroll
  for (int ks = 0; ks < 6; ++ks) {
    const int k0 = ks * 32;
#pragma unroll
    for (int r = 0; r < 2; ++r) {
      const int row = arow0 + r * 16 + lrow;
      if constexpr (CVTA) {
        const float* src = &((const float*)Ap)[(size_t)(m0 + row) * K + k0 + (lslot << 3)];
        const float4 f0 = *(const float4*)src;
        const float4 f1 = *(const float4*)(src + 4);
        bf16x8 h;
        h[0] = (short)f2bf(f0.x); h[1] = (short)f2bf(f0.y);
        h[2] = (short)f2bf(f0.z); h[3] = (short)f2bf(f0.w);
        h[4] = (short)f2bf(f1.x); h[5] = (short)f2bf(f1.y);
        h[6] = (short)f2bf(f1.z); h[7] = (short)f2bf(f1.w);
        const int sphys = lslot ^ (row & 3);
        *(bf16x8*)&sA[row * AST + (sphys << 3)] = h;
      } else {
        const size_t go = (size_t)(m0 + row) * K + k0 + ((lslot ^ (row & 3)) << 3);
        ld_g2l16(&((const unsigned short*)Ap)[go], &sA[(arow0 + r * 16) * AST]);
      }
    }
    __syncthreads();
#pragma unroll
    for (int i = 0; i < 4; ++i) {
      const int row = wr * 64 + i * 16 + fr_row;
      fah[ks][i] = *(const bf16x8*)&sA[row * AST + fr_swz];
    }
    __syncthreads();
  }

  // ---- phase 2: n-tile loop, B full-tile double-buffered -------------------
  auto stageB = [&](int buf, int nt_) {
#pragma unroll
    for (int s = 0; s < 6; ++s) {
      const size_t go = boff + (size_t)(nt_ * 64 + brow0 + lrow) * K + s * 32 + (ssl << 3);
      ld_g2l16(&Bh[go], &sB[buf][s][brow0 * 32]);
    }
  };

  stageB(0, 0);
  __syncthreads();
  const int er = (lane >> 4) << 2;  // C/D: col=lane&15, row=(lane>>4)*4+reg
  const int ec = lane & 15;
  for (int nt = 0; nt < NT; ++nt) {
    const int buf = nt & 1;
    if (nt < NT - 1) stageB(buf ^ 1, nt + 1);
    f32x4 acc[4][2] = {};
#pragma unroll
    for (int ks = 0; ks < 6; ++ks) {
      bf16x8 fbh[2];
#pragma unroll
      for (int j = 0; j < 2; ++j) {
        const int row = wc * 32 + j * 16 + fr_row;
        fbh[j] = *(const bf16x8*)&sB[buf][ks][row * 32 + fr_swz];
      }
#pragma unroll
      for (int i = 0; i < 4; ++i)
#pragma unroll
        for (int j = 0; j < 2; ++j)
          acc[i][j] = __builtin_amdgcn_mfma_f32_16x16x32_bf16(fah[ks][i], fbh[j], acc[i][j], 0, 0, 0);
    }
#pragma unroll
    for (int i = 0; i < 4; ++i)
#pragma unroll
      for (int j = 0; j < 2; ++j) {
        const size_t base = (size_t)(m0 + wr * 64 + i * 16 + er) * N + nt * 64 + wc * 32 + j * 16 + ec;
        if constexpr (OBF16) {
          unsigned short* cp = (unsigned short*)Co + base;
#pragma unroll
          for (int r = 0; r < 4; ++r) cp[(size_t)r * N] = f2bf(acc[i][j][r]);
        } else {
          float* cp = (float*)Co + base;
#pragma unroll
          for (int r = 0; r < 4; ++r) cp[(size_t)r * N] = acc[i][j][r];
        }
      }
    if (nt < NT - 1) __syncthreads();
  }
}

// ---- depthwise 3x3 SAME, rolling-window TY=8, bf16 in/out ------------------
// q,k -> bf16 qk[p][384]; v -> bf16 vh[p][192]
constexpr int TY = 8;
__global__ __launch_bounds__(256) void dwconv3x3_v5(const unsigned short* __restrict__ in,
                                                    const float* __restrict__ wdw,
                                                    unsigned short* __restrict__ qk,
                                                    unsigned short* __restrict__ vh) {
  const int t = blockIdx.x * 256 + threadIdx.x;
  const int c4 = t % 144;
  const int rest = t / 144;          // (img, ystrip, x)
  const int x = rest & 127;
  const int ys = (rest >> 7) & 15;   // 16 strips of TY=8
  const int img = rest >> 11;
  const int y0 = ys * TY;

  float4 wt[3][3];
#pragma unroll
  for (int i = 0; i < 3; ++i)
#pragma unroll
    for (int j = 0; j < 3; ++j)
      wt[i][j] = *(const float4*)&wdw[(size_t)(i * 3 + j) * C3 + c4 * 4];

  const bool xm = x > 0, xp = x < 127;
  const unsigned short* ibase = &in[((size_t)((img << 14) + x)) * C3 + c4 * 4];
  const float4 z4 = make_float4(0.f, 0.f, 0.f, 0.f);
  const ptrdiff_t dxm = xm ? -(ptrdiff_t)C3 : 0;   // clamped ptr + select-zero
  const ptrdiff_t dxp = xp ? (ptrdiff_t)C3 : 0;

  auto ldrow = [&](int yy, float4* r) {
    if ((unsigned)yy < 128u) {
      const unsigned short* rp = ibase + (size_t)yy * (128 * C3);
      float4 a = ld_bf4(rp + dxm);
      float4 m = ld_bf4(rp);
      float4 b = ld_bf4(rp + dxp);
      if (!xm) a = z4;
      if (!xp) b = z4;
      r[0] = a; r[1] = m; r[2] = b;
    } else {
      r[0] = z4; r[1] = z4; r[2] = z4;
    }
  };

  float4 r0[3], r1[3], r2[3], rn[3];
  ldrow(y0 - 1, r0);
  ldrow(y0, r1);
  ldrow(y0 + 1, r2);

#pragma unroll
  for (int i = 0; i < TY; ++i) {
    if (i < TY - 1) ldrow(y0 + i + 2, rn);  // prefetch overlaps compute below
    float4 o = z4;
#pragma unroll
    for (int j = 0; j < 3; ++j) {
      o.x += r0[j].x * wt[0][j].x; o.y += r0[j].y * wt[0][j].y;
      o.z += r0[j].z * wt[0][j].z; o.w += r0[j].w * wt[0][j].w;
      o.x += r1[j].x * wt[1][j].x; o.y += r1[j].y * wt[1][j].y;
      o.z += r1[j].z * wt[1][j].z; o.w += r1[j].w * wt[1][j].w;
      o.x += r2[j].x * wt[2][j].x; o.y += r2[j].y * wt[2][j].y;
      o.z += r2[j].z * wt[2][j].z; o.w += r2[j].w * wt[2][j].w;
    }
    const int p = (img << 14) + ((y0 + i) << 7) + x;
    const ushort4 ob = make_ushort4(f2bf(o.x), f2bf(o.y), f2bf(o.z), f2bf(o.w));
    if (c4 < 96) *(ushort4*)&qk[(size_t)p * 384 + c4 * 4] = ob;
    else         *(ushort4*)&vh[(size_t)p * 192 + (c4 - 96) * 4] = ob;
    if (i < TY - 1) {
#pragma unroll
      for (int j = 0; j < 3; ++j) { r0[j] = r1[j]; r1[j] = r2[j]; r2[j] = rn[j]; }
    }
  }
}

// ------- Gram v4 (MFMA, single-pass bf16): G = Q^T K per (img,h); + ssq -----
// qk bf16 [npix][384]: q = cols 0..191, k = cols 192..383.
// LDS: u32-packed PAIRS of channels, [128 rows][W=50]: q uints 0..23, k 24..47.
__global__ __launch_bounds__(256) void gram48_v4(const unsigned short* __restrict__ qk,
                                                 float* __restrict__ G,
                                                 float* __restrict__ ssqq,
                                                 float* __restrict__ ssqk) {
  constexpr int W = 50;
  __shared__ unsigned int smem[9216];   // staging uses 128*50=6400; reduce uses 9216
  const int tid = threadIdx.x;
  const int lane = tid & 63;
  const int wv = tid >> 6;
  const int pair = blockIdx.y;          // img*4 + h
  const int img = pair >> 2, h = pair & 3;

  f32x4 acc[3][3] = {};
  float ssq_acc = 0.f;
  const int sch = tid % 96;
  const int shalf = tid / 96;

  for (int rnd = 0; rnd < 2; ++rnd) {
    const int sbase = (img << 14) + blockIdx.x * 256 + rnd * 128;
#pragma unroll
    for (int r = 0; r < 6; ++r) {
      const int idx = tid + (r << 8);    // 0..1535 = 128 rows x 12 uint4
      const int row = idx / 12, part = idx % 12;
      const bool isq = part < 6;
      const int sub = isq ? part : part - 6;
      const uint4 v = *(const uint4*)&qk[(size_t)(sbase + row) * 384 + (isq ? 0 : 192) + h * 48 + sub * 8];
      *(uint4*)&smem[row * W + (isq ? 0 : 24) + sub * 4] = v;
    }
    __syncthreads();
    {
      const int s0 = wv * 32 + ((lane >> 4) << 3);
      const int cm = lane & 15;
      const int half = cm & 1;
      bf16x8 qf[3], kf[3];
#pragma unroll
      for (int t3 = 0; t3 < 3; ++t3) {
        const int qc = t3 * 8 + (cm >> 1);
#pragma unroll
        for (int j = 0; j < 8; ++j) {
          const unsigned uq = smem[(s0 + j) * W + qc];
          const unsigned uk = smem[(s0 + j) * W + 24 + qc];
          qf[t3][j] = (short)(half ? (uq >> 16) : (uq & 0xffffu));
          kf[t3][j] = (short)(half ? (uk >> 16) : (uk & 0xffffu));
        }
      }
#pragma unroll
      for (int mt = 0; mt < 3; ++mt)
#pragma unroll
        for (int nt = 0; nt < 3; ++nt)
          acc[mt][nt] = __builtin_amdgcn_mfma_f32_16x16x32_bf16(qf[mt], kf[nt], acc[mt][nt], 0, 0, 0);
    }
    if (tid < 192) {
      const int cu = (sch < 48) ? (sch >> 1) : 24 + ((sch - 48) >> 1);
      const int hf = sch & 1;
      const int sstart = shalf * 64;
#pragma unroll 4
      for (int s = 0; s < 64; ++s) {
        const unsigned u = smem[(sstart + s) * W + cu];
        const float v = bf2f((unsigned short)(hf ? (u >> 16) : (u & 0xffffu)));
        ssq_acc += v * v;
      }
    }
    __syncthreads();
  }

  // block reduce 4 wave-partials (reuse smem as floats), then atomics
  float* red = (float*)smem;
  const int col = lane & 15;
  const int rbase = (lane >> 4) * 4;
#pragma unroll
  for (int mt = 0; mt < 3; ++mt)
#pragma unroll
    for (int nt = 0; nt < 3; ++nt)
#pragma unroll
      for (int rg = 0; rg < 4; ++rg)
        red[wv * 2304 + (mt * 16 + rbase + rg) * 48 + nt * 16 + col] = acc[mt][nt][rg];
  __syncthreads();
  float* Gm = &G[(size_t)pair * 2304];
#pragma unroll
  for (int c = 0; c < 9; ++c) {
    const int cell = tid + (c << 8);
    const float s4 = red[cell] + red[2304 + cell] + red[4608 + cell] + red[6912 + cell];
    atomicAdd(&Gm[cell], s4);
  }
  if (tid < 192) {
    if (sch < 48) atomicAdd(&ssqq[img * 192 + h * 48 + sch], ssq_acc);
    else          atomicAdd(&ssqk[img * 192 + h * 48 + sch - 48], ssq_acc);
  }
}

// ---- softmax over d of G*temp/(|q||k|), one wave per (img,h,row) -----------
__global__ __launch_bounds__(64) void attn_softmax(const float* __restrict__ G,
                                                   const float* __restrict__ ssqq,
                                                   const float* __restrict__ ssqk,
                                                   const float* __restrict__ temp,
                                                   float* __restrict__ attn) {
  const int r = blockIdx.x;          // 0..47
  const int h = blockIdx.y & 3;
  const int img = blockIdx.y >> 2;
  const int lane = threadIdx.x;
  const size_t base = (size_t)(img * 4 + h) * 2304;
  const float t = temp[h];
  const float qn = ssqq[img * 192 + h * CH + r];
  float val = -1e30f;
  if (lane < 48) {
    const float kn = ssqk[img * 192 + h * CH + lane];
    val = G[base + r * 48 + lane] * t * rsqrtf(qn * kn);
  }
  float m = val;
#pragma unroll
  for (int off = 32; off; off >>= 1) m = fmaxf(m, __shfl_xor(m, off));
  const float e = (lane < 48) ? expf(val - m) : 0.f;
  float ssum = e;
#pragma unroll
  for (int off = 32; off; off >>= 1) ssum += __shfl_xor(ssum, off);
  if (lane < 48) attn[base + r * 48 + lane] = e / ssum;
}

// ---- W_eff^T[img][n][D] = sum_c' A[img][h(D)][c'][D%48] * Wp[48h+c'][n] ----
__global__ __launch_bounds__(256) void make_weff(const float* __restrict__ attn,
                                                 const float* __restrict__ wproj,
                                                 unsigned short* __restrict__ weh) {
  const int t = blockIdx.x * 256 + threadIdx.x;   // over 4*192*192
  const int img = t / 36864;
  const int r = t % 36864;
  const int n = r / 192;
  const int D = r % 192;
  const int h = D / 48, dd = D % 48;
  const float* A = &attn[(size_t)(img * 4 + h) * 2304 + dd];
  const float* Wp = &wproj[(size_t)(h * 48) * 192 + n];
  float acc = 0.f;
#pragma unroll
  for (int c = 0; c < 48; ++c) acc += A[c * 48] * Wp[c * 192];
  weh[(size_t)img * 36864 + n * 192 + D] = f2bf(acc);
}

}  // namespace

extern "C" void kernel_launch(void* const* d_in, const int* in_sizes, int n_in,
                              void* d_out, int out_size, void* d_ws, size_t ws_size,
                              hipStream_t stream) {
  const float* x      = (const float*)d_in[0];
  const float* w_qkv  = (const float*)d_in[1];
  const float* w_dw   = (const float*)d_in[2];
  const float* w_proj = (const float*)d_in[3];
  const float* temp   = (const float*)d_in[4];
  float* out = (float*)d_out;

  // NI images per pass. NI=4 ≈ 128 MB, fits the 256 MiB ws.
  auto layout_bytes = [](int NI) -> size_t {
    return (size_t)NI * HW * 576 * 2       // qkv bf16
         + (size_t)NI * HW * 384 * 2       // qk bf16
         + (size_t)NI * HW * 192 * 2       // vh (bf16)
         + 221184                          // wqh
         + 153600                          // G, ssqq, ssqk (all 4 images)
         + 147456                          // attnb (all 4 images)
         + 294912;                         // weh (all 4 images)
  };
  const int NI = (ws_size >= layout_bytes(4)) ? 4 : ((ws_size >= layout_bytes(2)) ? 2 : 1);
  const int npass = 4 / NI;
  const int npix = NI * HW;

  char* p = (char*)d_ws;
  unsigned short* qkv = (unsigned short*)p; p += (size_t)npix * 576 * 2;
  unsigned short* qk = (unsigned short*)p;  p += (size_t)npix * 384 * 2;
  unsigned short* vh = (unsigned short*)p;  p += (size_t)npix * 192 * 2;
  unsigned short* wqh = (unsigned short*)p; p += 221184;
  float* G    = (float*)p;           p += 147456;   // 16 (img,h) pairs
  float* ssqq = (float*)p;           p += 3072;     // 4 img x 192
  float* ssqk = (float*)p;           p += 3072;
  float* attnb = (float*)p;          p += 147456;
  unsigned short* weh = (unsigned short*)p;

  cvt_wqkv<<<432, 256, 0, stream>>>(w_qkv, wqh);
  hipMemsetAsync(G, 0, 153600, stream);  // G+ssqq+ssqk, all 4 images, once

  for (int pass = 0; pass < npass; ++pass) {
    const float* xb = x + (size_t)pass * npix * K;
    float* outb = out + (size_t)pass * npix * C;
    float* Gp    = G + (size_t)pass * NI * 4 * 2304;
    float* sqp   = ssqq + (size_t)pass * NI * 192;
    float* skp   = ssqk + (size_t)pass * NI * 192;
    float* ap    = attnb + (size_t)pass * NI * 4 * 2304;
    unsigned short* wehp = weh + (size_t)pass * NI * 36864;
    gemm_mfma<9, false, true, true><<<npix / 128, 256, 0, stream>>>(
        xb, wqh, qkv);
    dwconv3x3_v5<<<npix * 144 / TY / 256, 256, 0, stream>>>(qkv, w_dw, qk, vh);
    gram48_v4<<<dim3(64, 4 * NI), 256, 0, stream>>>(qk, Gp, sqp, skp);
    attn_softmax<<<dim3(48, 4 * NI), 64, 0, stream>>>(Gp, sqp, skp, temp, ap);
    make_weff<<<NI * 144, 256, 0, stream>>>(ap, w_proj, wehp);
    gemm_mfma<3, true, false, false><<<npix / 128, 256, 0, stream>>>(
        vh, wehp, outb);
  }
}

// Round 20
// 118.385 us; speedup vs baseline: 1.9325x; 1.0326x over previous
//
#include <hip/hip_runtime.h>

namespace {

constexpr int HW = 16384;   // pixels per image
constexpr int C  = 192;
constexpr int C3 = 576;
constexpr int CH = 48;
constexpr int K  = 192;

using bf16x8 = __attribute__((ext_vector_type(8))) short;
using f32x4  = __attribute__((ext_vector_type(4))) float;

__device__ inline unsigned short f2bf(float f) {
  unsigned u = __float_as_uint(f);
  unsigned r = (u + 0x7fff + ((u >> 16) & 1)) >> 16;
  return (unsigned short)r;
}
__device__ inline float bf2f(unsigned short b) {
  return __uint_as_float(((unsigned)b) << 16);
}
__device__ inline float4 ld_bf4(const unsigned short* p) {
  const ushort4 u = *(const ushort4*)p;
  return make_float4(bf2f(u.x), bf2f(u.y), bf2f(u.z), bf2f(u.w));
}

// async global->LDS, 16B per lane. LDS dest = wave-uniform base + lane*16.
__device__ __forceinline__ void ld_g2l16(const unsigned short* g, unsigned short* l) {
  __builtin_amdgcn_global_load_lds(
      (const __attribute__((address_space(1))) unsigned int*)(unsigned long long)(const void*)g,
      (__attribute__((address_space(3))) unsigned int*)(unsigned int)(unsigned long long)(void*)l,
      16, 0, 0);
}

// ---- transpose qkv weights: [192,576] -> bf16 [576][192] (hi only) ---------
__global__ __launch_bounds__(256) void cvt_wqkv(const float* __restrict__ wqkv,
                                                unsigned short* __restrict__ wqh) {
  const int t = blockIdx.x * 256 + threadIdx.x;  // 0 .. 576*192-1
  const int n = t / 192;
  const int k = t % 192;
  wqh[n * 192 + k] = f2bf(wqkv[k * C3 + n]);
}

// ---- MFMA GEMM: Co[M, NT*64] = A[M,192] @ B[NT*64,192]^T (bf16 1-pass) -----
// Block = 128 rows x ALL n-tiles, A in registers (fah[6][4]).
// Phase 2: B staged a FULL n-tile ahead (sB[2][6]) -> one barrier per n-tile.
// OBF16: bf16 output staged via LDS sC for coalesced b128 stores (the direct
// 2B/lane stores at 1152B row stride were ~4x the transaction count).
template <int NT, bool PERB, bool OBF16, bool CVTA>
__global__ __launch_bounds__(256) void gemm_mfma(const void* __restrict__ Ap,
                                                 const unsigned short* __restrict__ Bh,
                                                 void* __restrict__ Co) {
  constexpr int N = NT * 64;
  constexpr int AST = CVTA ? 40 : 32;   // A LDS row stride (ushorts)
  constexpr int CST = 72;               // sC row stride (16B-aligned, 4-bank shift)
  __shared__ __align__(16) unsigned short sA[128 * AST];
  __shared__ __align__(16) unsigned short sB[2][6][64 * 32];
  __shared__ __align__(16) unsigned short sC[OBF16 ? 128 * CST : 8];
  const int t = threadIdx.x;
  const int lane = t & 63;
  const int wv = t >> 6;
  const int m0 = blockIdx.x * 128;
  const size_t boff = PERB ? (size_t)(m0 >> 14) * (192 * 192) : 0;
  const int wr = wv >> 1, wc = wv & 1;
  const int fr_row = lane & 15;
  const int fr_swz = ((lane >> 4) ^ (lane & 3)) << 3;
  const int arow0 = wv * 32;           // A staging rows per wave (2 issues x 16)
  const int lrow  = lane >> 2;
  const int lslot = lane & 3;
  const int brow0 = wv * 16;           // B staging rows per wave
  const int ssl   = lslot ^ (lrow & 3);  // stage-side slot (row mod 4)

  // ---- phase 1: A -> registers, staged k-step by k-step --------------------
  bf16x8 fah[6][4];
#pragma unroll
  for (int ks = 0; ks < 6; ++ks) {
    const int k0 = ks * 32;
#pragma unroll
    for (int r = 0; r < 2; ++r) {
      const int row = arow0 + r * 16 + lrow;
      if constexpr (CVTA) {
        const float* src = &((const float*)Ap)[(size_t)(m0 + row) * K + k0 + (lslot << 3)];
        const float4 f0 = *(const float4*)src;
        const float4 f1 = *(const float4*)(src + 4);
        bf16x8 h;
        h[0] = (short)f2bf(f0.x); h[1] = (short)f2bf(f0.y);
        h[2] = (short)f2bf(f0.z); h[3] = (short)f2bf(f0.w);
        h[4] = (short)f2bf(f1.x); h[5] = (short)f2bf(f1.y);
        h[6] = (short)f2bf(f1.z); h[7] = (short)f2bf(f1.w);
        const int sphys = lslot ^ (row & 3);
        *(bf16x8*)&sA[row * AST + (sphys << 3)] = h;
      } else {
        const size_t go = (size_t)(m0 + row) * K + k0 + ((lslot ^ (row & 3)) << 3);
        ld_g2l16(&((const unsigned short*)Ap)[go], &sA[(arow0 + r * 16) * AST]);
      }
    }
    __syncthreads();
#pragma unroll
    for (int i = 0; i < 4; ++i) {
      const int row = wr * 64 + i * 16 + fr_row;
      fah[ks][i] = *(const bf16x8*)&sA[row * AST + fr_swz];
    }
    __syncthreads();
  }

  // ---- phase 2: n-tile loop, B full-tile double-buffered -------------------
  auto stageB = [&](int buf, int nt_) {
#pragma unroll
    for (int s = 0; s < 6; ++s) {
      const size_t go = boff + (size_t)(nt_ * 64 + brow0 + lrow) * K + s * 32 + (ssl << 3);
      ld_g2l16(&Bh[go], &sB[buf][s][brow0 * 32]);
    }
  };

  stageB(0, 0);
  __syncthreads();
  const int er = (lane >> 4) << 2;  // C/D: col=lane&15, row=(lane>>4)*4+reg
  const int ec = lane & 15;
  for (int nt = 0; nt < NT; ++nt) {
    const int buf = nt & 1;
    if (nt < NT - 1) stageB(buf ^ 1, nt + 1);
    f32x4 acc[4][2] = {};
#pragma unroll
    for (int ks = 0; ks < 6; ++ks) {
      bf16x8 fbh[2];
#pragma unroll
      for (int j = 0; j < 2; ++j) {
        const int row = wc * 32 + j * 16 + fr_row;
        fbh[j] = *(const bf16x8*)&sB[buf][ks][row * 32 + fr_swz];
      }
#pragma unroll
      for (int i = 0; i < 4; ++i)
#pragma unroll
        for (int j = 0; j < 2; ++j)
          acc[i][j] = __builtin_amdgcn_mfma_f32_16x16x32_bf16(fah[ks][i], fbh[j], acc[i][j], 0, 0, 0);
    }
    if constexpr (OBF16) {
      // stage accumulator -> sC, then coalesced b128 stores
#pragma unroll
      for (int i = 0; i < 4; ++i)
#pragma unroll
        for (int j = 0; j < 2; ++j)
#pragma unroll
          for (int r = 0; r < 4; ++r)
            sC[(wr * 64 + i * 16 + er + r) * CST + wc * 32 + j * 16 + ec] = f2bf(acc[i][j][r]);
      __syncthreads();
#pragma unroll
      for (int it = 0; it < 4; ++it) {
        const int idx = t + it * 256;
        const int row = idx >> 3, seg = idx & 7;
        *(bf16x8*)&((unsigned short*)Co)[(size_t)(m0 + row) * N + nt * 64 + seg * 8] =
            *(const bf16x8*)&sC[row * CST + seg * 8];
      }
    } else {
#pragma unroll
      for (int i = 0; i < 4; ++i)
#pragma unroll
        for (int j = 0; j < 2; ++j) {
          const size_t base = (size_t)(m0 + wr * 64 + i * 16 + er) * N + nt * 64 + wc * 32 + j * 16 + ec;
          float* cp = (float*)Co + base;
#pragma unroll
          for (int r = 0; r < 4; ++r) cp[(size_t)r * N] = acc[i][j][r];
        }
    }
    if (nt < NT - 1) __syncthreads();
  }
}

// ---- depthwise 3x3 SAME, rolling-window TY=8, prefetch depth 2, bf16 -------
// q,k -> bf16 qk[p][384]; v -> bf16 vh[p][192]
constexpr int TY = 8;
__global__ __launch_bounds__(256) void dwconv3x3_v6(const unsigned short* __restrict__ in,
                                                    const float* __restrict__ wdw,
                                                    unsigned short* __restrict__ qk,
                                                    unsigned short* __restrict__ vh) {
  const int t = blockIdx.x * 256 + threadIdx.x;
  const int c4 = t % 144;
  const int rest = t / 144;          // (img, ystrip, x)
  const int x = rest & 127;
  const int ys = (rest >> 7) & 15;   // 16 strips of TY=8
  const int img = rest >> 11;
  const int y0 = ys * TY;

  float4 wt[3][3];
#pragma unroll
  for (int i = 0; i < 3; ++i)
#pragma unroll
    for (int j = 0; j < 3; ++j)
      wt[i][j] = *(const float4*)&wdw[(size_t)(i * 3 + j) * C3 + c4 * 4];

  const bool xm = x > 0, xp = x < 127;
  const unsigned short* ibase = &in[((size_t)((img << 14) + x)) * C3 + c4 * 4];
  const float4 z4 = make_float4(0.f, 0.f, 0.f, 0.f);
  const ptrdiff_t dxm = xm ? -(ptrdiff_t)C3 : 0;   // clamped ptr + select-zero
  const ptrdiff_t dxp = xp ? (ptrdiff_t)C3 : 0;

  auto ldrow = [&](int yy, float4* r) {
    if ((unsigned)yy < 128u) {
      const unsigned short* rp = ibase + (size_t)yy * (128 * C3);
      float4 a = ld_bf4(rp + dxm);
      float4 m = ld_bf4(rp);
      float4 b = ld_bf4(rp + dxp);
      if (!xm) a = z4;
      if (!xp) b = z4;
      r[0] = a; r[1] = m; r[2] = b;
    } else {
      r[0] = z4; r[1] = z4; r[2] = z4;
    }
  };

  float4 r0[3], r1[3], r2[3];
  float4 pf[2][3];                    // two prefetch rows in flight
  ldrow(y0 - 1, r0);
  ldrow(y0, r1);
  ldrow(y0 + 1, r2);
  ldrow(y0 + 2, pf[0]);

#pragma unroll
  for (int i = 0; i < TY; ++i) {
    if (i < TY - 2) ldrow(y0 + i + 3, pf[(i + 1) & 1]);  // 2 rows ahead
    float4 o = z4;
#pragma unroll
    for (int j = 0; j < 3; ++j) {
      o.x += r0[j].x * wt[0][j].x; o.y += r0[j].y * wt[0][j].y;
      o.z += r0[j].z * wt[0][j].z; o.w += r0[j].w * wt[0][j].w;
      o.x += r1[j].x * wt[1][j].x; o.y += r1[j].y * wt[1][j].y;
      o.z += r1[j].z * wt[1][j].z; o.w += r1[j].w * wt[1][j].w;
      o.x += r2[j].x * wt[2][j].x; o.y += r2[j].y * wt[2][j].y;
      o.z += r2[j].z * wt[2][j].z; o.w += r2[j].w * wt[2][j].w;
    }
    const int p = (img << 14) + ((y0 + i) << 7) + x;
    const ushort4 ob = make_ushort4(f2bf(o.x), f2bf(o.y), f2bf(o.z), f2bf(o.w));
    if (c4 < 96) *(ushort4*)&qk[(size_t)p * 384 + c4 * 4] = ob;
    else         *(ushort4*)&vh[(size_t)p * 192 + (c4 - 96) * 4] = ob;
    if (i < TY - 1) {
#pragma unroll
      for (int j = 0; j < 3; ++j) { r0[j] = r1[j]; r1[j] = r2[j]; r2[j] = pf[i & 1][j]; }
    }
  }
}

// ------- Gram v4 (MFMA, single-pass bf16): G = Q^T K per (img,h); + ssq -----
// qk bf16 [npix][384]: q = cols 0..191, k = cols 192..383.
// LDS: u32-packed PAIRS of channels, [128 rows][W=50]: q uints 0..23, k 24..47.
__global__ __launch_bounds__(256) void gram48_v4(const unsigned short* __restrict__ qk,
                                                 float* __restrict__ G,
                                                 float* __restrict__ ssqq,
                                                 float* __restrict__ ssqk) {
  constexpr int W = 50;
  __shared__ unsigned int smem[9216];   // staging uses 128*50=6400; reduce uses 9216
  const int tid = threadIdx.x;
  const int lane = tid & 63;
  const int wv = tid >> 6;
  const int pair = blockIdx.y;          // img*4 + h
  const int img = pair >> 2, h = pair & 3;

  f32x4 acc[3][3] = {};
  float ssq_acc = 0.f;
  const int sch = tid % 96;
  const int shalf = tid / 96;

  for (int rnd = 0; rnd < 2; ++rnd) {
    const int sbase = (img << 14) + blockIdx.x * 256 + rnd * 128;
#pragma unroll
    for (int r = 0; r < 6; ++r) {
      const int idx = tid + (r << 8);    // 0..1535 = 128 rows x 12 uint4
      const int row = idx / 12, part = idx % 12;
      const bool isq = part < 6;
      const int sub = isq ? part : part - 6;
      const uint4 v = *(const uint4*)&qk[(size_t)(sbase + row) * 384 + (isq ? 0 : 192) + h * 48 + sub * 8];
      *(uint4*)&smem[row * W + (isq ? 0 : 24) + sub * 4] = v;
    }
    __syncthreads();
    {
      const int s0 = wv * 32 + ((lane >> 4) << 3);
      const int cm = lane & 15;
      const int half = cm & 1;
      bf16x8 qf[3], kf[3];
#pragma unroll
      for (int t3 = 0; t3 < 3; ++t3) {
        const int qc = t3 * 8 + (cm >> 1);
#pragma unroll
        for (int j = 0; j < 8; ++j) {
          const unsigned uq = smem[(s0 + j) * W + qc];
          const unsigned uk = smem[(s0 + j) * W + 24 + qc];
          qf[t3][j] = (short)(half ? (uq >> 16) : (uq & 0xffffu));
          kf[t3][j] = (short)(half ? (uk >> 16) : (uk & 0xffffu));
        }
      }
#pragma unroll
      for (int mt = 0; mt < 3; ++mt)
#pragma unroll
        for (int nt = 0; nt < 3; ++nt)
          acc[mt][nt] = __builtin_amdgcn_mfma_f32_16x16x32_bf16(qf[mt], kf[nt], acc[mt][nt], 0, 0, 0);
    }
    if (tid < 192) {
      const int cu = (sch < 48) ? (sch >> 1) : 24 + ((sch - 48) >> 1);
      const int hf = sch & 1;
      const int sstart = shalf * 64;
#pragma unroll 4
      for (int s = 0; s < 64; ++s) {
        const unsigned u = smem[(sstart + s) * W + cu];
        const float v = bf2f((unsigned short)(hf ? (u >> 16) : (u & 0xffffu)));
        ssq_acc += v * v;
      }
    }
    __syncthreads();
  }

  // block reduce 4 wave-partials (reuse smem as floats), then atomics
  float* red = (float*)smem;
  const int col = lane & 15;
  const int rbase = (lane >> 4) * 4;
#pragma unroll
  for (int mt = 0; mt < 3; ++mt)
#pragma unroll
    for (int nt = 0; nt < 3; ++nt)
#pragma unroll
      for (int rg = 0; rg < 4; ++rg)
        red[wv * 2304 + (mt * 16 + rbase + rg) * 48 + nt * 16 + col] = acc[mt][nt][rg];
  __syncthreads();
  float* Gm = &G[(size_t)pair * 2304];
#pragma unroll
  for (int c = 0; c < 9; ++c) {
    const int cell = tid + (c << 8);
    const float s4 = red[cell] + red[2304 + cell] + red[4608 + cell] + red[6912 + cell];
    atomicAdd(&Gm[cell], s4);
  }
  if (tid < 192) {
    if (sch < 48) atomicAdd(&ssqq[img * 192 + h * 48 + sch], ssq_acc);
    else          atomicAdd(&ssqk[img * 192 + h * 48 + sch - 48], ssq_acc);
  }
}

// ---- softmax over d of G*temp/(|q||k|), one wave per (img,h,row) -----------
__global__ __launch_bounds__(64) void attn_softmax(const float* __restrict__ G,
                                                   const float* __restrict__ ssqq,
                                                   const float* __restrict__ ssqk,
                                                   const float* __restrict__ temp,
                                                   float* __restrict__ attn) {
  const int r = blockIdx.x;          // 0..47
  const int h = blockIdx.y & 3;
  const int img = blockIdx.y >> 2;
  const int lane = threadIdx.x;
  const size_t base = (size_t)(img * 4 + h) * 2304;
  const float t = temp[h];
  const float qn = ssqq[img * 192 + h * CH + r];
  float val = -1e30f;
  if (lane < 48) {
    const float kn = ssqk[img * 192 + h * CH + lane];
    val = G[base + r * 48 + lane] * t * rsqrtf(qn * kn);
  }
  float m = val;
#pragma unroll
  for (int off = 32; off; off >>= 1) m = fmaxf(m, __shfl_xor(m, off));
  const float e = (lane < 48) ? expf(val - m) : 0.f;
  float ssum = e;
#pragma unroll
  for (int off = 32; off; off >>= 1) ssum += __shfl_xor(ssum, off);
  if (lane < 48) attn[base + r * 48 + lane] = e / ssum;
}

// ---- W_eff^T[img][n][D] = sum_c' A[img][h(D)][c'][D%48] * Wp[48h+c'][n] ----
__global__ __launch_bounds__(256) void make_weff(const float* __restrict__ attn,
                                                 const float* __restrict__ wproj,
                                                 unsigned short* __restrict__ weh) {
  const int t = blockIdx.x * 256 + threadIdx.x;   // over 4*192*192
  const int img = t / 36864;
  const int r = t % 36864;
  const int n = r / 192;
  const int D = r % 192;
  const int h = D / 48, dd = D % 48;
  const float* A = &attn[(size_t)(img * 4 + h) * 2304 + dd];
  const float* Wp = &wproj[(size_t)(h * 48) * 192 + n];
  float acc = 0.f;
#pragma unroll
  for (int c = 0; c < 48; ++c) acc += A[c * 48] * Wp[c * 192];
  weh[(size_t)img * 36864 + n * 192 + D] = f2bf(acc);
}

}  // namespace

extern "C" void kernel_launch(void* const* d_in, const int* in_sizes, int n_in,
                              void* d_out, int out_size, void* d_ws, size_t ws_size,
                              hipStream_t stream) {
  const float* x      = (const float*)d_in[0];
  const float* w_qkv  = (const float*)d_in[1];
  const float* w_dw   = (const float*)d_in[2];
  const float* w_proj = (const float*)d_in[3];
  const float* temp   = (const float*)d_in[4];
  float* out = (float*)d_out;

  // NI images per pass. NI=4 ≈ 128 MB, fits the 256 MiB ws.
  auto layout_bytes = [](int NI) -> size_t {
    return (size_t)NI * HW * 576 * 2       // qkv bf16
         + (size_t)NI * HW * 384 * 2       // qk bf16
         + (size_t)NI * HW * 192 * 2       // vh (bf16)
         + 221184                          // wqh
         + 153600                          // G, ssqq, ssqk (all 4 images)
         + 147456                          // attnb (all 4 images)
         + 294912;                         // weh (all 4 images)
  };
  const int NI = (ws_size >= layout_bytes(4)) ? 4 : ((ws_size >= layout_bytes(2)) ? 2 : 1);
  const int npass = 4 / NI;
  const int npix = NI * HW;

  char* p = (char*)d_ws;
  unsigned short* qkv = (unsigned short*)p; p += (size_t)npix * 576 * 2;
  unsigned short* qk = (unsigned short*)p;  p += (size_t)npix * 384 * 2;
  unsigned short* vh = (unsigned short*)p;  p += (size_t)npix * 192 * 2;
  unsigned short* wqh = (unsigned short*)p; p += 221184;
  float* G    = (float*)p;           p += 147456;   // 16 (img,h) pairs
  float* ssqq = (float*)p;           p += 3072;     // 4 img x 192
  float* ssqk = (float*)p;           p += 3072;
  float* attnb = (float*)p;          p += 147456;
  unsigned short* weh = (unsigned short*)p;

  cvt_wqkv<<<432, 256, 0, stream>>>(w_qkv, wqh);
  hipMemsetAsync(G, 0, 153600, stream);  // G+ssqq+ssqk, all 4 images, once

  for (int pass = 0; pass < npass; ++pass) {
    const float* xb = x + (size_t)pass * npix * K;
    float* outb = out + (size_t)pass * npix * C;
    float* Gp    = G + (size_t)pass * NI * 4 * 2304;
    float* sqp   = ssqq + (size_t)pass * NI * 192;
    float* skp   = ssqk + (size_t)pass * NI * 192;
    float* ap    = attnb + (size_t)pass * NI * 4 * 2304;
    unsigned short* wehp = weh + (size_t)pass * NI * 36864;
    gemm_mfma<9, false, true, true><<<npix / 128, 256, 0, stream>>>(
        xb, wqh, qkv);
    dwconv3x3_v6<<<npix * 144 / TY / 256, 256, 0, stream>>>(qkv, w_dw, qk, vh);
    gram48_v4<<<dim3(64, 4 * NI), 256, 0, stream>>>(qk, Gp, sqp, skp);
    attn_softmax<<<dim3(48, 4 * NI), 64, 0, stream>>>(Gp, sqp, skp, temp, ap);
    make_weff<<<NI * 144, 256, 0, stream>>>(ap, w_proj, wehp);
    gemm_mfma<3, true, false, false><<<npix / 128, 256, 0, stream>>>(
        vh, wehp, outb);
  }
}